// Round 2
// baseline (3125.601 us; speedup 1.0000x reference)
//
#include <hip/hip_runtime.h>

// ---------------------------------------------------------------------------
// Transolver forward, MI355X. Round 2: dtype-adaptive (runtime bf16/fp32
// sniff via temp[0] low ushort), bf16 intermediates (ws cut 209MB -> 126MB).
// Pipeline: cvt(params->fp32) + prep(weights->fp32 swizzled) -> pre-MLP ->
// 5x[LN, GEMMx2, slice-softmax, tok-reduce, attn(64x64), deslice, GEMM+res,
// LN, MLP GEMMx2] -> LN -> head.
// ---------------------------------------------------------------------------

#define MTOK 32768   // B*N
#define NB   16384   // N

typedef unsigned short u16;

__device__ __forceinline__ float bfu(u16 u) {
    return __uint_as_float(((unsigned)u) << 16);
}
__device__ __forceinline__ u16 f2bf(float f) {
    unsigned u = __float_as_uint(f);
    u += 0x7FFFu + ((u >> 16) & 1u);   // round-to-nearest-even
    return (u16)(u >> 16);
}
__device__ __forceinline__ float ldf(const void* p, int i, int isbf) {
    return isbf ? bfu(((const u16*)p)[i]) : ((const float*)p)[i];
}
__device__ __forceinline__ float4 dec4(ushort4 u) {
    return make_float4(bfu(u.x), bfu(u.y), bfu(u.z), bfu(u.w));
}
__device__ __forceinline__ float gelu_f(float x) {
    return 0.5f * x * (1.0f + erff(x * 0.7071067811865475f));
}

// ---------------- workspace layout (float-unit offsets) --------------------
#define F_H      ((size_t)0)          // fp32 residual [32768,256]
#define F_TOK    ((size_t)8388608)    // fp32 [16,2048]
#define F_NORM   ((size_t)8421376)    // fp32 [16,64]
#define F_OS     ((size_t)8422400)    // fp32 [16,2048]
#define F_WSW    ((size_t)8455168)    // fp32 swizzled weights + biases
#define F_PARAMS ((size_t)10297088)   // fp32 converted small params
#define F_BF     ((size_t)10559232)   // bf16 region base (cast to u16*)
// bf16 region (u16-unit offsets from U base)
#define U_Y   ((size_t)0)             // [32768,256]
#define U_XM  ((size_t)8388608)       // [32768,256]; with U_FM doubles as HID [32768,512]
#define U_FM  ((size_t)16777216)      // [32768,256]
#define U_SW  ((size_t)25165824)      // [16,16384,64]
// total ws bytes: 42,236,928 + 83,886,080 = 126,123,008 (~120.3 MB)

// wsw-internal offsets (floats)
#define W_PRE2   0
#define W_HEAD1  131072
#define W_PX     196608
#define W_PFX    524288
#define W_OUT    851968
#define W_MLP1   1179648
#define W_MLP2   1507328
#define W_TOTAL  1835008
#define W_PB2C   1835008
#define W_PXB    1835264
#define W_PFXB   1836544
#define W_OUTB   1837824
#define W_M1B    1839104
#define W_M2B    1840384
#define W_HB1    1841664
#define W_END    1841920

// params-internal offsets (floats, relative to F_PARAMS)
#define P_X    0
#define P_FX   65536
#define P_W1   196608
#define P_B1   199680
#define P_LN1G 200192
#define P_LN1B 201472
#define P_LN2G 202752
#define P_LN2B 204032
#define P_LN3G 205312
#define P_LN3B 205568
#define P_SLW  205824
#define P_SLB  216064
#define P_TEMP 216384
#define P_QW   216448
#define P_KW   221568
#define P_VW   226688
#define P_HW2  231808
#define P_HB2  232832
#define P_END  232836

// ---------------- cvt: small params -> fp32 params region ------------------
__global__ __launch_bounds__(256) void cvt_kernel(
    const void* x, const void* fx, const void* w1, const void* b1,
    const void* l1g, const void* l1b, const void* l2g, const void* l2b,
    const void* l3g, const void* l3b, const void* slw, const void* slb,
    const void* tmp, const void* qw, const void* kw, const void* vw,
    const void* hw2, const void* hb2, float* __restrict__ P)
{
    int isbf = (((const u16*)tmp)[0] != 0);
    int idx = blockIdx.x * 256 + threadIdx.x;
    const void* s; int o;
    if      (idx < 65536)  { s = x;   o = idx; }
    else if (idx < 196608) { s = fx;  o = idx - 65536; }
    else if (idx < 199680) { s = w1;  o = idx - 196608; }
    else if (idx < 200192) { s = b1;  o = idx - 199680; }
    else if (idx < 201472) { s = l1g; o = idx - 200192; }
    else if (idx < 202752) { s = l1b; o = idx - 201472; }
    else if (idx < 204032) { s = l2g; o = idx - 202752; }
    else if (idx < 205312) { s = l2b; o = idx - 204032; }
    else if (idx < 205568) { s = l3g; o = idx - 205312; }
    else if (idx < 205824) { s = l3b; o = idx - 205568; }
    else if (idx < 216064) { s = slw; o = idx - 205824; }
    else if (idx < 216384) { s = slb; o = idx - 216064; }
    else if (idx < 216424) { s = tmp; o = idx - 216384; }
    else if (idx < 216448) { return; }
    else if (idx < 221568) { s = qw;  o = idx - 216448; }
    else if (idx < 226688) { s = kw;  o = idx - 221568; }
    else if (idx < 231808) { s = vw;  o = idx - 226688; }
    else if (idx < 232832) { s = hw2; o = idx - 231808; }
    else if (idx < 232836) { s = hb2; o = idx - 232832; }
    else return;
    P[idx] = ldf(s, o, isbf);
}

// ---------------- prep: big weights -> fp32 swizzled [K/4][256][4] ---------
__global__ __launch_bounds__(256) void prep_kernel(
    const void* pre_w2, const void* head_w1, const void* px_w, const void* pfx_w,
    const void* out_w, const void* mlp_w1, const void* mlp_w2, const void* pre_b2,
    const void* placeholder, const void* px_b, const void* pfx_b, const void* out_b,
    const void* mlp_b1, const void* mlp_b2, const void* head_b1, const void* tmp,
    float* __restrict__ wsw)
{
    int isbf = (((const u16*)tmp)[0] != 0);
    int idx = blockIdx.x * 256 + threadIdx.x;
    if (idx < 131072) {                       // pre_w2  (K=512)
        int k4 = idx >> 10, r = idx & 1023, c = r >> 2, i = r & 3;
        wsw[idx] = ldf(pre_w2, (k4 * 4 + i) * 256 + c, isbf);
    } else if (idx < W_TOTAL) {               // 26 K=256 matrices
        int f = idx - 131072;
        int mat = f >> 16;
        int r = f & 65535;
        const void* s; int off = 0;
        if      (mat == 0)  { s = head_w1; }
        else if (mat <= 5)  { s = px_w;   off = (mat - 1)  * 65536; }
        else if (mat <= 10) { s = pfx_w;  off = (mat - 6)  * 65536; }
        else if (mat <= 15) { s = out_w;  off = (mat - 11) * 65536; }
        else if (mat <= 20) { s = mlp_w1; off = (mat - 16) * 65536; }
        else                { s = mlp_w2; off = (mat - 21) * 65536; }
        int k4 = r >> 10, rr = r & 1023, c = rr >> 2, i = rr & 3;
        wsw[idx] = ldf(s, off + (k4 * 4 + i) * 256 + c, isbf);
    } else if (idx < W_TOTAL + 256) {         // pre_b2 + placeholder combined
        int c = idx - W_TOTAL;
        wsw[idx] = ldf(pre_b2, c, isbf) + ldf(placeholder, c, isbf);
    } else if (idx < W_END) {                 // fp32 biases
        int o = idx - W_PXB;
        float v;
        if      (o < 1280) v = ldf(px_b,   o,        isbf);
        else if (o < 2560) v = ldf(pfx_b,  o - 1280, isbf);
        else if (o < 3840) v = ldf(out_b,  o - 2560, isbf);
        else if (o < 5120) v = ldf(mlp_b1, o - 3840, isbf);
        else if (o < 6400) v = ldf(mlp_b2, o - 5120, isbf);
        else               v = ldf(head_b1, o - 6400, isbf);
        wsw[idx] = v;
    }
}

// ---------------- preprocess stage 1: gelu(in6 @ pre_w1 + b1) -> bf16 ------
__global__ __launch_bounds__(256) void pre1_kernel(
    const float* __restrict__ P, u16* __restrict__ HID)
{
    int idx = blockIdx.x * 256 + threadIdx.x;   // < M*512
    int m = idx >> 9, j = idx & 511;
    const float* xx = P + P_X;
    const float* ff = P + P_FX;
    const float* w1 = P + P_W1;
    float a = P[P_B1 + j];
    a = fmaf(xx[m * 2 + 0], w1[0 * 512 + j], a);
    a = fmaf(xx[m * 2 + 1], w1[1 * 512 + j], a);
    a = fmaf(ff[m * 4 + 0], w1[2 * 512 + j], a);
    a = fmaf(ff[m * 4 + 1], w1[3 * 512 + j], a);
    a = fmaf(ff[m * 4 + 2], w1[4 * 512 + j], a);
    a = fmaf(ff[m * 4 + 3], w1[5 * 512 + j], a);
    HID[idx] = f2bf(gelu_f(a));
}

// ---------------- token-GEMM: C[M,256] = f(A[M,KK]bf16 @ W + b) ------------
// Wt fp32 swizzled [K/4][256][4]; block=256, 64 tokens; wave w -> tokens
// w*16..+15; lane owns cols {l, l+64, l+128, l+192}.
// OMODE: 0 = fp32 store, 1 = fp32 read-add-store (residual), 2 = bf16 store,
//        3 = gelu then bf16 store.
template <int KK, int OMODE>
__global__ __launch_bounds__(256) void gemm_k(
    const u16* __restrict__ A, const float* __restrict__ Wt,
    const float* __restrict__ bias, float* __restrict__ C, u16* __restrict__ Cb)
{
    __shared__ float As[64 * 256];
    const int t = threadIdx.x;
    const int wave = t >> 6, lane = t & 63;
    const int m0 = blockIdx.x * 64;
    float acc[16][4];
#pragma unroll
    for (int m = 0; m < 16; ++m) {
        acc[m][0] = 0.f; acc[m][1] = 0.f; acc[m][2] = 0.f; acc[m][3] = 0.f;
    }
    const float4* Wt4 = (const float4*)Wt;
    for (int ko = 0; ko < KK / 256; ++ko) {
        if (ko) __syncthreads();
#pragma unroll
        for (int i = 0; i < 16; ++i) {
            int f4 = t + 256 * i;
            int row = f4 >> 6, c4 = f4 & 63;
            ushort4 u = *(const ushort4*)(A + (size_t)(m0 + row) * KK + ko * 256 + c4 * 4);
            *(float4*)(As + row * 256 + c4 * 4) = dec4(u);
        }
        __syncthreads();
        const float* Asw = As + wave * 16 * 256;
#pragma unroll 2
        for (int k4 = 0; k4 < 64; ++k4) {
            int wbase = (ko * 64 + k4) * 256 + lane;
            float4 w0 = Wt4[wbase];
            float4 w1 = Wt4[wbase + 64];
            float4 w2 = Wt4[wbase + 128];
            float4 w3 = Wt4[wbase + 192];
            const float* ap = Asw + k4 * 4;
#pragma unroll
            for (int m = 0; m < 16; ++m) {
                float4 a = *(const float4*)(ap + m * 256);
                acc[m][0] = fmaf(a.w, w0.w, fmaf(a.z, w0.z, fmaf(a.y, w0.y, fmaf(a.x, w0.x, acc[m][0]))));
                acc[m][1] = fmaf(a.w, w1.w, fmaf(a.z, w1.z, fmaf(a.y, w1.y, fmaf(a.x, w1.x, acc[m][1]))));
                acc[m][2] = fmaf(a.w, w2.w, fmaf(a.z, w2.z, fmaf(a.y, w2.y, fmaf(a.x, w2.x, acc[m][2]))));
                acc[m][3] = fmaf(a.w, w3.w, fmaf(a.z, w3.z, fmaf(a.y, w3.y, fmaf(a.x, w3.x, acc[m][3]))));
            }
        }
    }
    float b0 = bias[lane], b1 = bias[lane + 64], b2 = bias[lane + 128], b3 = bias[lane + 192];
#pragma unroll
    for (int m = 0; m < 16; ++m) {
        size_t base = (size_t)(m0 + wave * 16 + m) * 256 + lane;
        float v0 = acc[m][0] + b0, v1 = acc[m][1] + b1;
        float v2 = acc[m][2] + b2, v3 = acc[m][3] + b3;
        if (OMODE == 3) { v0 = gelu_f(v0); v1 = gelu_f(v1); v2 = gelu_f(v2); v3 = gelu_f(v3); }
        if (OMODE == 1) { v0 += C[base]; v1 += C[base + 64]; v2 += C[base + 128]; v3 += C[base + 192]; }
        if (OMODE >= 2) {
            Cb[base] = f2bf(v0); Cb[base + 64] = f2bf(v1);
            Cb[base + 128] = f2bf(v2); Cb[base + 192] = f2bf(v3);
        } else {
            C[base] = v0; C[base + 64] = v1; C[base + 128] = v2; C[base + 192] = v3;
        }
    }
}

// ---------------- LayerNorm: fp32 in -> bf16 out (wave per token) ----------
__global__ __launch_bounds__(256) void ln_kernel(
    const float* __restrict__ X, const float* __restrict__ g,
    const float* __restrict__ b, u16* __restrict__ Y)
{
    int lane = threadIdx.x & 63;
    size_t m = (size_t)blockIdx.x * 4 + (threadIdx.x >> 6);
    const float4 x4 = *(const float4*)(X + m * 256 + lane * 4);
    float s = x4.x + x4.y + x4.z + x4.w;
    float q = x4.x * x4.x + x4.y * x4.y + x4.z * x4.z + x4.w * x4.w;
#pragma unroll
    for (int o = 32; o; o >>= 1) { s += __shfl_xor(s, o); q += __shfl_xor(q, o); }
    float mean = s * (1.0f / 256.0f);
    float var = q * (1.0f / 256.0f) - mean * mean;
    float inv = 1.0f / sqrtf(var + 1e-5f);
    const float4 g4 = *(const float4*)(g + lane * 4);
    const float4 b4 = *(const float4*)(b + lane * 4);
    ushort4 y;
    y.x = f2bf((x4.x - mean) * inv * g4.x + b4.x);
    y.y = f2bf((x4.y - mean) * inv * g4.y + b4.y);
    y.z = f2bf((x4.z - mean) * inv * g4.z + b4.z);
    y.w = f2bf((x4.w - mean) * inv * g4.w + b4.w);
    *(ushort4*)(Y + m * 256 + lane * 4) = y;
}

// ---------------- slice logits + softmax over G=64 (wave per (m,hd)) -------
__global__ __launch_bounds__(256) void slice_kernel(
    const u16* __restrict__ XM, const float* __restrict__ slw,
    const float* __restrict__ slb, const float* __restrict__ tempv,
    u16* __restrict__ SW)
{
    int p = blockIdx.x * 4 + (threadIdx.x >> 6);  // (m,hd) pair
    int g = threadIdx.x & 63;
    int m = p >> 3, hd = p & 7;
    const u16* xr = XM + (size_t)m * 256 + hd * 32;
    float a = slb[g];
#pragma unroll
    for (int d = 0; d < 32; ++d) a = fmaf(bfu(xr[d]), slw[d * 64 + g], a);
    a /= tempv[hd];
    float mx = a;
#pragma unroll
    for (int o = 32; o; o >>= 1) mx = fmaxf(mx, __shfl_xor(mx, o));
    float e = expf(a - mx);
    float ssum = e;
#pragma unroll
    for (int o = 32; o; o >>= 1) ssum += __shfl_xor(ssum, o);
    int b = m >> 14, n = m & 16383;
    SW[(((size_t)(b * 8 + hd)) * NB + n) * 64 + g] = f2bf(e / ssum);
}

// ---------------- tok reduction over N (+ norm) ----------------------------
__global__ __launch_bounds__(256) void tok_kernel(
    const u16* __restrict__ FM, const u16* __restrict__ SW,
    float* __restrict__ TOK, float* __restrict__ NORM)
{
    int bh = blockIdx.x >> 6, chunk = blockIdx.x & 63;
    int b = bh >> 3, hd = bh & 7;
    int t = threadIdx.x, wave = t >> 6, lane = t & 63;
    int g0 = (lane >> 3) * 8, d0 = (lane & 7) * 4;
    float4 acc[8];
#pragma unroll
    for (int gi = 0; gi < 8; ++gi) acc[gi] = make_float4(0.f, 0.f, 0.f, 0.f);
    float4 n0a = make_float4(0.f, 0.f, 0.f, 0.f);
    float4 n1a = make_float4(0.f, 0.f, 0.f, 0.f);
    int nbase = chunk * 256 + wave * 64;
    const u16* fmB = FM + ((size_t)b * NB + nbase) * 256 + hd * 32 + d0;
    const u16* swB = SW + ((size_t)bh * NB + nbase) * 64 + g0;
    for (int j = 0; j < 64; ++j) {
        float4 f4 = dec4(*(const ushort4*)(fmB + (size_t)j * 256));
        float4 s0 = dec4(*(const ushort4*)(swB + (size_t)j * 64));
        float4 s1 = dec4(*(const ushort4*)(swB + (size_t)j * 64 + 4));
#define TOKACC(gi, sv)                                            \
        acc[gi].x = fmaf(f4.x, sv, acc[gi].x);                    \
        acc[gi].y = fmaf(f4.y, sv, acc[gi].y);                    \
        acc[gi].z = fmaf(f4.z, sv, acc[gi].z);                    \
        acc[gi].w = fmaf(f4.w, sv, acc[gi].w);
        TOKACC(0, s0.x) TOKACC(1, s0.y) TOKACC(2, s0.z) TOKACC(3, s0.w)
        TOKACC(4, s1.x) TOKACC(5, s1.y) TOKACC(6, s1.z) TOKACC(7, s1.w)
#undef TOKACC
        n0a.x += s0.x; n0a.y += s0.y; n0a.z += s0.z; n0a.w += s0.w;
        n1a.x += s1.x; n1a.y += s1.y; n1a.z += s1.z; n1a.w += s1.w;
    }
    __shared__ float red[4][2048];
    __shared__ float nred[4][64];
#pragma unroll
    for (int gi = 0; gi < 8; ++gi)
        *(float4*)&red[wave][(g0 + gi) * 32 + d0] = acc[gi];
    if ((lane & 7) == 0) {
        nred[wave][g0 + 0] = n0a.x; nred[wave][g0 + 1] = n0a.y;
        nred[wave][g0 + 2] = n0a.z; nred[wave][g0 + 3] = n0a.w;
        nred[wave][g0 + 4] = n1a.x; nred[wave][g0 + 5] = n1a.y;
        nred[wave][g0 + 6] = n1a.z; nred[wave][g0 + 7] = n1a.w;
    }
    __syncthreads();
    size_t tokBase = (size_t)bh * 2048;
#pragma unroll
    for (int k = 0; k < 8; ++k) {
        int c = t + 256 * k;
        atomicAdd(&TOK[tokBase + c], red[0][c] + red[1][c] + red[2][c] + red[3][c]);
    }
    if (t < 64)
        atomicAdd(&NORM[bh * 64 + t], nred[0][t] + nred[1][t] + nred[2][t] + nred[3][t]);
}

// ---------------- attention over G=64 tokens (block per (b,h)) -------------
__global__ __launch_bounds__(256) void attn_kernel(
    const float* __restrict__ TOK, const float* __restrict__ NORM,
    const float* __restrict__ qw, const float* __restrict__ kw,
    const float* __restrict__ vw, float* __restrict__ OS)
{
    __shared__ float tokd[2048], qs[2048], ks[2048], vs[2048];
    int bh = blockIdx.x;
    int t = threadIdx.x;
#pragma unroll
    for (int i = 0; i < 2; ++i) {
        int f4 = t + 256 * i;
        float4 v = *(const float4*)(TOK + (size_t)bh * 2048 + f4 * 4);
        float inv = 1.0f / (NORM[bh * 64 + (f4 >> 3)] + 1e-5f);
        v.x *= inv; v.y *= inv; v.z *= inv; v.w *= inv;
        *(float4*)&tokd[f4 * 4] = v;
    }
    __syncthreads();
#pragma unroll
    for (int i = 0; i < 8; ++i) {
        int f = t + 256 * i;
        int g = f >> 5, d = f & 31;
        const float* tr = tokd + g * 32;
        float aq = 0.f, ak = 0.f, av = 0.f;
#pragma unroll
        for (int e = 0; e < 32; ++e) {
            float tv = tr[e];
            aq = fmaf(tv, qw[e * 32 + d], aq);
            ak = fmaf(tv, kw[e * 32 + d], ak);
            av = fmaf(tv, vw[e * 32 + d], av);
        }
        qs[f] = aq; ks[f] = ak; vs[f] = av;
    }
    __syncthreads();
    int g = t >> 2, sub = t & 3;
    float4 qv[8];
#pragma unroll
    for (int e4 = 0; e4 < 8; ++e4) qv[e4] = *(const float4*)(qs + g * 32 + e4 * 4);
    float p[16];
    float mx = -3.0e38f;
#pragma unroll
    for (int mm = 0; mm < 16; ++mm) {
        int mI = sub * 16 + mm;
        const float4* kr = (const float4*)(ks + mI * 32);
        float s = 0.f;
#pragma unroll
        for (int e4 = 0; e4 < 8; ++e4) {
            float4 kv = kr[e4];
            s = fmaf(qv[e4].x, kv.x, s); s = fmaf(qv[e4].y, kv.y, s);
            s = fmaf(qv[e4].z, kv.z, s); s = fmaf(qv[e4].w, kv.w, s);
        }
        s *= 0.17677669529663687f;   // 1/sqrt(32)
        p[mm] = s;
        mx = fmaxf(mx, s);
    }
    mx = fmaxf(mx, __shfl_xor(mx, 1));
    mx = fmaxf(mx, __shfl_xor(mx, 2));
    float lsum = 0.f;
#pragma unroll
    for (int mm = 0; mm < 16; ++mm) { p[mm] = expf(p[mm] - mx); lsum += p[mm]; }
    lsum += __shfl_xor(lsum, 1);
    lsum += __shfl_xor(lsum, 2);
    float inv = 1.0f / lsum;
    float4 oa[8];
#pragma unroll
    for (int d4 = 0; d4 < 8; ++d4) oa[d4] = make_float4(0.f, 0.f, 0.f, 0.f);
#pragma unroll
    for (int mm = 0; mm < 16; ++mm) {
        int mI = sub * 16 + mm;
        const float4* vr = (const float4*)(vs + mI * 32);
        float pm = p[mm];
#pragma unroll
        for (int d4 = 0; d4 < 8; ++d4) {
            float4 vv = vr[d4];
            oa[d4].x = fmaf(pm, vv.x, oa[d4].x);
            oa[d4].y = fmaf(pm, vv.y, oa[d4].y);
            oa[d4].z = fmaf(pm, vv.z, oa[d4].z);
            oa[d4].w = fmaf(pm, vv.w, oa[d4].w);
        }
    }
#pragma unroll
    for (int d4 = 0; d4 < 8; ++d4) {
        oa[d4].x += __shfl_xor(oa[d4].x, 1); oa[d4].x += __shfl_xor(oa[d4].x, 2);
        oa[d4].y += __shfl_xor(oa[d4].y, 1); oa[d4].y += __shfl_xor(oa[d4].y, 2);
        oa[d4].z += __shfl_xor(oa[d4].z, 1); oa[d4].z += __shfl_xor(oa[d4].z, 2);
        oa[d4].w += __shfl_xor(oa[d4].w, 1); oa[d4].w += __shfl_xor(oa[d4].w, 2);
    }
    float4 r0 = oa[sub * 2], r1 = oa[sub * 2 + 1];
    r0.x *= inv; r0.y *= inv; r0.z *= inv; r0.w *= inv;
    r1.x *= inv; r1.y *= inv; r1.z *= inv; r1.w *= inv;
    *(float4*)(OS + (size_t)bh * 2048 + g * 32 + sub * 8)     = r0;
    *(float4*)(OS + (size_t)bh * 2048 + g * 32 + sub * 8 + 4) = r1;
}

// ---------------- deslice: out_x = einsum(out_slice, sw) -> bf16 -----------
__global__ __launch_bounds__(256) void deslice_kernel(
    const float* __restrict__ OS, const u16* __restrict__ SW, u16* __restrict__ OX)
{
    __shared__ float swt[8 * 16 * 64];   // [hd][mm][g]
    int blk = blockIdx.x;
    int b = blk >> 10, n0 = (blk & 1023) * 16;
    int t = threadIdx.x;
    int hd = t >> 5, d = t & 31;
#pragma unroll
    for (int i = 0; i < 8; ++i) {
        int f4 = t + 256 * i;
        int hd2 = f4 >> 8, mm = (f4 >> 4) & 15, g4 = f4 & 15;
        ushort4 u = *(const ushort4*)(SW + (((size_t)(b * 8 + hd2)) * NB + n0 + mm) * 64 + g4 * 4);
        *(float4*)&swt[(hd2 * 16 + mm) * 64 + g4 * 4] = dec4(u);
    }
    __syncthreads();
    float acc[16];
#pragma unroll
    for (int mm = 0; mm < 16; ++mm) acc[mm] = 0.f;
    const float* osb = OS + ((size_t)(b * 8 + hd)) * 2048 + d;
#pragma unroll 4
    for (int g4 = 0; g4 < 16; ++g4) {
        float o0 = osb[(g4 * 4 + 0) * 32], o1 = osb[(g4 * 4 + 1) * 32];
        float o2 = osb[(g4 * 4 + 2) * 32], o3 = osb[(g4 * 4 + 3) * 32];
        const float* swp = swt + hd * 1024 + g4 * 4;
#pragma unroll
        for (int mm = 0; mm < 16; ++mm) {
            float4 sv = *(const float4*)(swp + mm * 64);
            acc[mm] = fmaf(o0, sv.x, fmaf(o1, sv.y, fmaf(o2, sv.z, fmaf(o3, sv.w, acc[mm]))));
        }
    }
#pragma unroll
    for (int mm = 0; mm < 16; ++mm)
        OX[((size_t)b * NB + n0 + mm) * 256 + t] = f2bf(acc[mm]);
}

// ---------------- head stage 2: out = hid @ head_w2 + b2 -------------------
__global__ __launch_bounds__(256) void head2_kernel(
    const u16* __restrict__ HID, const float* __restrict__ w2,
    const float* __restrict__ b2, const void* tmp, void* __restrict__ OUT)
{
    int isbf = (((const u16*)tmp)[0] != 0);
    int lane = threadIdx.x & 63;
    size_t m = (size_t)blockIdx.x * 4 + (threadIdx.x >> 6);
    const float4 hv = dec4(*(const ushort4*)(HID + m * 256 + lane * 4));
    float4 a = make_float4(0.f, 0.f, 0.f, 0.f);
    float hcomp[4] = {hv.x, hv.y, hv.z, hv.w};
#pragma unroll
    for (int i = 0; i < 4; ++i) {
        const float4 wv = *(const float4*)(w2 + (lane * 4 + i) * 4);
        float h = hcomp[i];
        a.x = fmaf(h, wv.x, a.x); a.y = fmaf(h, wv.y, a.y);
        a.z = fmaf(h, wv.z, a.z); a.w = fmaf(h, wv.w, a.w);
    }
#pragma unroll
    for (int o = 32; o; o >>= 1) {
        a.x += __shfl_xor(a.x, o); a.y += __shfl_xor(a.y, o);
        a.z += __shfl_xor(a.z, o); a.w += __shfl_xor(a.w, o);
    }
    if (lane == 0) {
        float o0 = a.x + b2[0], o1 = a.y + b2[1], o2 = a.z + b2[2], o3 = a.w + b2[3];
        if (isbf) {
            ushort4 r; r.x = f2bf(o0); r.y = f2bf(o1); r.z = f2bf(o2); r.w = f2bf(o3);
            *(ushort4*)((u16*)OUT + m * 4) = r;
        } else {
            *(float4*)((float*)OUT + m * 4) = make_float4(o0, o1, o2, o3);
        }
    }
}

// ---------------------------------------------------------------------------
extern "C" void kernel_launch(void* const* d_in, const int* in_sizes, int n_in,
                              void* d_out, int out_size, void* d_ws, size_t ws_size,
                              hipStream_t stream)
{
    const void* x = d_in[0];      const void* fx = d_in[1];
    const void* pre_w1 = d_in[2]; const void* pre_b1 = d_in[3];
    const void* pre_w2 = d_in[4]; const void* pre_b2 = d_in[5];
    const void* placeholder = d_in[6];
    const void* ln1_g = d_in[7];  const void* ln1_b = d_in[8];
    const void* px_w = d_in[9];   const void* px_b = d_in[10];
    const void* pfx_w = d_in[11]; const void* pfx_b = d_in[12];
    const void* slice_w = d_in[13]; const void* slice_b = d_in[14];
    const void* temp = d_in[15];
    const void* q_w = d_in[16];   const void* k_w = d_in[17]; const void* v_w = d_in[18];
    const void* out_w = d_in[19]; const void* out_b = d_in[20];
    const void* ln2_g = d_in[21]; const void* ln2_b = d_in[22];
    const void* mlp_w1 = d_in[23]; const void* mlp_b1 = d_in[24];
    const void* mlp_w2 = d_in[25]; const void* mlp_b2 = d_in[26];
    const void* ln3_g = d_in[27]; const void* ln3_b = d_in[28];
    const void* head_w1 = d_in[29]; const void* head_b1 = d_in[30];
    const void* head_w2 = d_in[31]; const void* head_b2 = d_in[32];

    float* ws = (float*)d_ws;
    float* H     = ws + F_H;
    float* TOKp  = ws + F_TOK;
    float* NORMp = ws + F_NORM;
    float* OSp   = ws + F_OS;
    float* WSW   = ws + F_WSW;
    float* P     = ws + F_PARAMS;
    u16*   U     = (u16*)(ws + F_BF);
    u16*   Yb    = U + U_Y;
    u16*   XMb   = U + U_XM;
    u16*   FMb   = U + U_FM;
    u16*   SWb   = U + U_SW;
    u16*   HIDb  = U + U_XM;   // [M,512] spans XM+FM (free before layer loop)

    cvt_kernel<<<910, 256, 0, stream>>>(x, fx, pre_w1, pre_b1, ln1_g, ln1_b,
        ln2_g, ln2_b, ln3_g, ln3_b, slice_w, slice_b, temp, q_w, k_w, v_w,
        head_w2, head_b2, P);
    prep_kernel<<<7195, 256, 0, stream>>>(pre_w2, head_w1, px_w, pfx_w, out_w,
        mlp_w1, mlp_w2, pre_b2, placeholder, px_b, pfx_b, out_b, mlp_b1, mlp_b2,
        head_b1, temp, WSW);
    pre1_kernel<<<65536, 256, 0, stream>>>(P, HIDb);
    gemm_k<512, 0><<<512, 256, 0, stream>>>(HIDb, WSW + W_PRE2, WSW + W_PB2C, H, nullptr);

    for (int i = 0; i < 5; ++i) {
        ln_kernel<<<8192, 256, 0, stream>>>(H, P + P_LN1G + i * 256, P + P_LN1B + i * 256, Yb);
        gemm_k<256, 2><<<512, 256, 0, stream>>>(Yb, WSW + W_PX  + i * 65536, WSW + W_PXB  + i * 256, nullptr, XMb);
        gemm_k<256, 2><<<512, 256, 0, stream>>>(Yb, WSW + W_PFX + i * 65536, WSW + W_PFXB + i * 256, nullptr, FMb);
        slice_kernel<<<65536, 256, 0, stream>>>(XMb, P + P_SLW + i * 2048, P + P_SLB + i * 64, P + P_TEMP + i * 8, SWb);
        hipMemsetAsync(TOKp, 0, (size_t)33792 * 4, stream);
        tok_kernel<<<1024, 256, 0, stream>>>(FMb, SWb, TOKp, NORMp);
        attn_kernel<<<16, 256, 0, stream>>>(TOKp, NORMp, P + P_QW + i * 1024, P + P_KW + i * 1024, P + P_VW + i * 1024, OSp);
        deslice_kernel<<<2048, 256, 0, stream>>>(OSp, SWb, Yb);
        gemm_k<256, 1><<<512, 256, 0, stream>>>(Yb, WSW + W_OUT + i * 65536, WSW + W_OUTB + i * 256, H, nullptr);
        ln_kernel<<<8192, 256, 0, stream>>>(H, P + P_LN2G + i * 256, P + P_LN2B + i * 256, Yb);
        gemm_k<256, 3><<<512, 256, 0, stream>>>(Yb,  WSW + W_MLP1 + i * 65536, WSW + W_M1B + i * 256, nullptr, XMb);
        gemm_k<256, 1><<<512, 256, 0, stream>>>(XMb, WSW + W_MLP2 + i * 65536, WSW + W_M2B + i * 256, H, nullptr);
    }

    ln_kernel<<<8192, 256, 0, stream>>>(H, P + P_LN3G, P + P_LN3B, Yb);
    gemm_k<256, 3><<<512, 256, 0, stream>>>(Yb, WSW + W_HEAD1, WSW + W_HB1, nullptr, XMb);
    head2_kernel<<<8192, 256, 0, stream>>>(XMb, P + P_HW2, P + P_HB2, temp, d_out);
}

// Round 3
// 1722.944 us; speedup vs baseline: 1.8141x; 1.8141x over previous
//
#include <hip/hip_runtime.h>

// ---------------------------------------------------------------------------
// Transolver forward, MI355X. Round 3: MFMA bf16 GEMMs (16x16x32), weights
// pre-transposed to [N][K] bf16. Rest of pipeline unchanged from passing R2.
// ---------------------------------------------------------------------------

#define MTOK 32768   // B*N
#define NB   16384   // N

typedef unsigned short u16;
using short8 = __attribute__((ext_vector_type(8))) short;
using f4     = __attribute__((ext_vector_type(4))) float;

__device__ __forceinline__ float bfu(u16 u) {
    return __uint_as_float(((unsigned)u) << 16);
}
__device__ __forceinline__ u16 f2bf(float f) {
    unsigned u = __float_as_uint(f);
    u += 0x7FFFu + ((u >> 16) & 1u);   // round-to-nearest-even
    return (u16)(u >> 16);
}
__device__ __forceinline__ float ldf(const void* p, int i, int isbf) {
    return isbf ? bfu(((const u16*)p)[i]) : ((const float*)p)[i];
}
__device__ __forceinline__ float4 dec4(ushort4 u) {
    return make_float4(bfu(u.x), bfu(u.y), bfu(u.z), bfu(u.w));
}
__device__ __forceinline__ float gelu_f(float x) {
    return 0.5f * x * (1.0f + erff(x * 0.7071067811865475f));
}

// ---------------- workspace layout -----------------------------------------
// fp32 region (float offsets)
#define F_H      ((size_t)0)          // fp32 residual [32768,256]
#define F_TOK    ((size_t)8388608)
#define F_NORM   ((size_t)8421376)
#define F_OS     ((size_t)8422400)
#define F_BIAS   ((size_t)8455168)    // fp32 biases (6912)
#define F_PARAMS ((size_t)8462080)    // fp32 small params (232836)
#define F_BF     ((size_t)8694920)    // u16 region base (even-aligned)
// bias-internal (floats, rel to F_BIAS)
#define B_PB2C 0
#define B_PXB  256
#define B_PFXB 1536
#define B_OUTB 2816
#define B_M1B  4096
#define B_M2B  5376
#define B_HB1  6656
#define B_END  6912
// u16 region offsets
#define U_WT  ((size_t)0)            // transposed bf16 weights (1835008)
#define WT_PRE2  0                   // [256][512]
#define WT_HEAD1 131072              // [256][256] each below
#define WT_PX    196608
#define WT_PFX   524288
#define WT_OUT   851968
#define WT_MLP1  1179648
#define WT_MLP2  1507328
#define WT_END   1835008
#define U_Y   ((size_t)1835008)      // [32768,256] bf16
#define U_XM  ((size_t)10223616)     // [32768,256]; +FM doubles as HID [32768,512]
#define U_FM  ((size_t)18612224)
#define U_SW  ((size_t)27000832)     // [16,16384,64]
// total ws: 8694920*4 + 43778048*2 = 122,335,776 B (~117 MB)

// params-internal offsets (floats, rel to F_PARAMS)
#define P_X    0
#define P_FX   65536
#define P_W1   196608
#define P_B1   199680
#define P_LN1G 200192
#define P_LN1B 201472
#define P_LN2G 202752
#define P_LN2B 204032
#define P_LN3G 205312
#define P_LN3B 205568
#define P_SLW  205824
#define P_SLB  216064
#define P_TEMP 216384
#define P_QW   216448
#define P_KW   221568
#define P_VW   226688
#define P_HW2  231808
#define P_HB2  232832
#define P_END  232836

// ---------------- cvt: small params -> fp32 params region ------------------
__global__ __launch_bounds__(256) void cvt_kernel(
    const void* x, const void* fx, const void* w1, const void* b1,
    const void* l1g, const void* l1b, const void* l2g, const void* l2b,
    const void* l3g, const void* l3b, const void* slw, const void* slb,
    const void* tmp, const void* qw, const void* kw, const void* vw,
    const void* hw2, const void* hb2, float* __restrict__ P)
{
    int isbf = (((const u16*)tmp)[0] != 0);
    int idx = blockIdx.x * 256 + threadIdx.x;
    const void* s; int o;
    if      (idx < 65536)  { s = x;   o = idx; }
    else if (idx < 196608) { s = fx;  o = idx - 65536; }
    else if (idx < 199680) { s = w1;  o = idx - 196608; }
    else if (idx < 200192) { s = b1;  o = idx - 199680; }
    else if (idx < 201472) { s = l1g; o = idx - 200192; }
    else if (idx < 202752) { s = l1b; o = idx - 201472; }
    else if (idx < 204032) { s = l2g; o = idx - 202752; }
    else if (idx < 205312) { s = l2b; o = idx - 204032; }
    else if (idx < 205568) { s = l3g; o = idx - 205312; }
    else if (idx < 205824) { s = l3b; o = idx - 205568; }
    else if (idx < 216064) { s = slw; o = idx - 205824; }
    else if (idx < 216384) { s = slb; o = idx - 216064; }
    else if (idx < 216424) { s = tmp; o = idx - 216384; }
    else if (idx < 216448) { return; }
    else if (idx < 221568) { s = qw;  o = idx - 216448; }
    else if (idx < 226688) { s = kw;  o = idx - 221568; }
    else if (idx < 231808) { s = vw;  o = idx - 226688; }
    else if (idx < 232832) { s = hw2; o = idx - 231808; }
    else if (idx < 232836) { s = hb2; o = idx - 232832; }
    else return;
    P[idx] = ldf(s, o, isbf);
}

// ---------------- prep: weights -> bf16 W^T [N][K]; biases -> fp32 ---------
__global__ __launch_bounds__(256) void prep_kernel(
    const void* pre_w2, const void* head_w1, const void* px_w, const void* pfx_w,
    const void* out_w, const void* mlp_w1, const void* mlp_w2, const void* pre_b2,
    const void* placeholder, const void* px_b, const void* pfx_b, const void* out_b,
    const void* mlp_b1, const void* mlp_b2, const void* head_b1, const void* tmp,
    u16* __restrict__ WT, float* __restrict__ BIAS)
{
    int isbf = (((const u16*)tmp)[0] != 0);
    int idx = blockIdx.x * 256 + threadIdx.x;
    if (idx < 131072) {                       // pre_w2 [512,256] -> [256][512]
        int n = idx >> 9, k = idx & 511;
        WT[idx] = f2bf(ldf(pre_w2, k * 256 + n, isbf));
    } else if (idx < WT_END) {                // 26 [256,256] matrices
        int f = idx - 131072;
        int mat = f >> 16;
        int r = f & 65535;
        const void* s; int off = 0;
        if      (mat == 0)  { s = head_w1; }
        else if (mat <= 5)  { s = px_w;   off = (mat - 1)  * 65536; }
        else if (mat <= 10) { s = pfx_w;  off = (mat - 6)  * 65536; }
        else if (mat <= 15) { s = out_w;  off = (mat - 11) * 65536; }
        else if (mat <= 20) { s = mlp_w1; off = (mat - 16) * 65536; }
        else                { s = mlp_w2; off = (mat - 21) * 65536; }
        int n = r >> 8, k = r & 255;
        WT[idx] = f2bf(ldf(s, off + k * 256 + n, isbf));
    } else if (idx < WT_END + 256) {          // pb2c = pre_b2 + placeholder
        int c = idx - WT_END;
        BIAS[B_PB2C + c] = ldf(pre_b2, c, isbf) + ldf(placeholder, c, isbf);
    } else if (idx < WT_END + B_END) {        // fp32 biases
        int o = idx - (WT_END + 256);
        float v;
        if      (o < 1280) v = ldf(px_b,   o,        isbf);
        else if (o < 2560) v = ldf(pfx_b,  o - 1280, isbf);
        else if (o < 3840) v = ldf(out_b,  o - 2560, isbf);
        else if (o < 5120) v = ldf(mlp_b1, o - 3840, isbf);
        else if (o < 6400) v = ldf(mlp_b2, o - 5120, isbf);
        else               v = ldf(head_b1, o - 6400, isbf);
        BIAS[B_PXB + o] = v;
    }
}

// ---------------- preprocess stage 1: gelu(in6 @ pre_w1 + b1) -> bf16 ------
__global__ __launch_bounds__(256) void pre1_kernel(
    const float* __restrict__ P, u16* __restrict__ HID)
{
    int idx = blockIdx.x * 256 + threadIdx.x;   // < M*512
    int m = idx >> 9, j = idx & 511;
    const float* xx = P + P_X;
    const float* ff = P + P_FX;
    const float* w1 = P + P_W1;
    float a = P[P_B1 + j];
    a = fmaf(xx[m * 2 + 0], w1[0 * 512 + j], a);
    a = fmaf(xx[m * 2 + 1], w1[1 * 512 + j], a);
    a = fmaf(ff[m * 4 + 0], w1[2 * 512 + j], a);
    a = fmaf(ff[m * 4 + 1], w1[3 * 512 + j], a);
    a = fmaf(ff[m * 4 + 2], w1[4 * 512 + j], a);
    a = fmaf(ff[m * 4 + 3], w1[5 * 512 + j], a);
    HID[idx] = f2bf(gelu_f(a));
}

// ---------------- MFMA GEMM: C[M,256] = f(A[M,KK]bf16 @ W + b) -------------
// Wt bf16 [256][KK] (N-major). Block: 128x128 tile, 4 waves 2x2 of 64x64.
// OMODE: 0 fp32 store, 1 fp32 +=residual, 2 bf16 store, 3 gelu->bf16 store.
template <int KK, int OMODE>
__global__ __launch_bounds__(256, 2) void gemm_mfma(
    const u16* __restrict__ A, const u16* __restrict__ Wt,
    const float* __restrict__ bias, float* __restrict__ C, u16* __restrict__ Cb)
{
    __shared__ u16 As[128 * 72];
    __shared__ u16 Bs[128 * 72];
    const int t = threadIdx.x;
    const int wave = t >> 6, lane = t & 63;
    const int quad = lane >> 4, l15 = lane & 15;
    const int m0 = blockIdx.x * 128;
    const int n0 = blockIdx.y * 128;
    const int wm = (wave & 1) * 64, wn = (wave >> 1) * 64;
    f4 acc[4][4];
#pragma unroll
    for (int i = 0; i < 4; ++i)
#pragma unroll
        for (int j = 0; j < 4; ++j)
            acc[i][j] = (f4){0.f, 0.f, 0.f, 0.f};

    for (int kc = 0; kc < KK; kc += 64) {
        if (kc) __syncthreads();
#pragma unroll
        for (int i = 0; i < 4; ++i) {
            int c = t + 256 * i;
            int row = c >> 3, col = (c & 7) * 8;
            *(ulonglong2*)(As + row * 72 + col) =
                *(const ulonglong2*)(A + (size_t)(m0 + row) * KK + kc + col);
            *(ulonglong2*)(Bs + row * 72 + col) =
                *(const ulonglong2*)(Wt + (size_t)(n0 + row) * KK + kc + col);
        }
        __syncthreads();
#pragma unroll
        for (int k32 = 0; k32 < 64; k32 += 32) {
            short8 a[4], b[4];
#pragma unroll
            for (int i = 0; i < 4; ++i)
                a[i] = *(const short8*)(As + (wm + i * 16 + l15) * 72 + k32 + quad * 8);
#pragma unroll
            for (int j = 0; j < 4; ++j)
                b[j] = *(const short8*)(Bs + (wn + j * 16 + l15) * 72 + k32 + quad * 8);
#pragma unroll
            for (int i = 0; i < 4; ++i)
#pragma unroll
                for (int j = 0; j < 4; ++j)
                    acc[i][j] = __builtin_amdgcn_mfma_f32_16x16x32_bf16(
                        a[i], b[j], acc[i][j], 0, 0, 0);
        }
    }
#pragma unroll
    for (int j = 0; j < 4; ++j) {
        int cj = n0 + wn + j * 16 + l15;
        float bj = bias[cj];
#pragma unroll
        for (int i = 0; i < 4; ++i) {
            int rbase = m0 + wm + i * 16 + quad * 4;
#pragma unroll
            for (int r = 0; r < 4; ++r) {
                float v = acc[i][j][r] + bj;
                size_t off = (size_t)(rbase + r) * 256 + cj;
                if (OMODE == 3) v = gelu_f(v);
                if (OMODE == 1) v += C[off];
                if (OMODE >= 2) Cb[off] = f2bf(v);
                else            C[off] = v;
            }
        }
    }
}

// ---------------- LayerNorm: fp32 in -> bf16 out (wave per token) ----------
__global__ __launch_bounds__(256) void ln_kernel(
    const float* __restrict__ X, const float* __restrict__ g,
    const float* __restrict__ b, u16* __restrict__ Y)
{
    int lane = threadIdx.x & 63;
    size_t m = (size_t)blockIdx.x * 4 + (threadIdx.x >> 6);
    const float4 x4 = *(const float4*)(X + m * 256 + lane * 4);
    float s = x4.x + x4.y + x4.z + x4.w;
    float q = x4.x * x4.x + x4.y * x4.y + x4.z * x4.z + x4.w * x4.w;
#pragma unroll
    for (int o = 32; o; o >>= 1) { s += __shfl_xor(s, o); q += __shfl_xor(q, o); }
    float mean = s * (1.0f / 256.0f);
    float var = q * (1.0f / 256.0f) - mean * mean;
    float inv = 1.0f / sqrtf(var + 1e-5f);
    const float4 g4 = *(const float4*)(g + lane * 4);
    const float4 b4 = *(const float4*)(b + lane * 4);
    ushort4 y;
    y.x = f2bf((x4.x - mean) * inv * g4.x + b4.x);
    y.y = f2bf((x4.y - mean) * inv * g4.y + b4.y);
    y.z = f2bf((x4.z - mean) * inv * g4.z + b4.z);
    y.w = f2bf((x4.w - mean) * inv * g4.w + b4.w);
    *(ushort4*)(Y + m * 256 + lane * 4) = y;
}

// ---------------- slice logits + softmax over G=64 (wave per (m,hd)) -------
__global__ __launch_bounds__(256) void slice_kernel(
    const u16* __restrict__ XM, const float* __restrict__ slw,
    const float* __restrict__ slb, const float* __restrict__ tempv,
    u16* __restrict__ SW)
{
    int p = blockIdx.x * 4 + (threadIdx.x >> 6);  // (m,hd) pair
    int g = threadIdx.x & 63;
    int m = p >> 3, hd = p & 7;
    const u16* xr = XM + (size_t)m * 256 + hd * 32;
    float a = slb[g];
#pragma unroll
    for (int d = 0; d < 32; ++d) a = fmaf(bfu(xr[d]), slw[d * 64 + g], a);
    a /= tempv[hd];
    float mx = a;
#pragma unroll
    for (int o = 32; o; o >>= 1) mx = fmaxf(mx, __shfl_xor(mx, o));
    float e = expf(a - mx);
    float ssum = e;
#pragma unroll
    for (int o = 32; o; o >>= 1) ssum += __shfl_xor(ssum, o);
    int b = m >> 14, n = m & 16383;
    SW[(((size_t)(b * 8 + hd)) * NB + n) * 64 + g] = f2bf(e / ssum);
}

// ---------------- tok reduction over N (+ norm) ----------------------------
__global__ __launch_bounds__(256) void tok_kernel(
    const u16* __restrict__ FM, const u16* __restrict__ SW,
    float* __restrict__ TOK, float* __restrict__ NORM)
{
    int bh = blockIdx.x >> 6, chunk = blockIdx.x & 63;
    int b = bh >> 3, hd = bh & 7;
    int t = threadIdx.x, wave = t >> 6, lane = t & 63;
    int g0 = (lane >> 3) * 8, d0 = (lane & 7) * 4;
    float4 acc[8];
#pragma unroll
    for (int gi = 0; gi < 8; ++gi) acc[gi] = make_float4(0.f, 0.f, 0.f, 0.f);
    float4 n0a = make_float4(0.f, 0.f, 0.f, 0.f);
    float4 n1a = make_float4(0.f, 0.f, 0.f, 0.f);
    int nbase = chunk * 256 + wave * 64;
    const u16* fmB = FM + ((size_t)b * NB + nbase) * 256 + hd * 32 + d0;
    const u16* swB = SW + ((size_t)bh * NB + nbase) * 64 + g0;
    for (int j = 0; j < 64; ++j) {
        float4 f4v = dec4(*(const ushort4*)(fmB + (size_t)j * 256));
        float4 s0 = dec4(*(const ushort4*)(swB + (size_t)j * 64));
        float4 s1 = dec4(*(const ushort4*)(swB + (size_t)j * 64 + 4));
#define TOKACC(gi, sv)                                            \
        acc[gi].x = fmaf(f4v.x, sv, acc[gi].x);                   \
        acc[gi].y = fmaf(f4v.y, sv, acc[gi].y);                   \
        acc[gi].z = fmaf(f4v.z, sv, acc[gi].z);                   \
        acc[gi].w = fmaf(f4v.w, sv, acc[gi].w);
        TOKACC(0, s0.x) TOKACC(1, s0.y) TOKACC(2, s0.z) TOKACC(3, s0.w)
        TOKACC(4, s1.x) TOKACC(5, s1.y) TOKACC(6, s1.z) TOKACC(7, s1.w)
#undef TOKACC
        n0a.x += s0.x; n0a.y += s0.y; n0a.z += s0.z; n0a.w += s0.w;
        n1a.x += s1.x; n1a.y += s1.y; n1a.z += s1.z; n1a.w += s1.w;
    }
    __shared__ float red[4][2048];
    __shared__ float nred[4][64];
#pragma unroll
    for (int gi = 0; gi < 8; ++gi)
        *(float4*)&red[wave][(g0 + gi) * 32 + d0] = acc[gi];
    if ((lane & 7) == 0) {
        nred[wave][g0 + 0] = n0a.x; nred[wave][g0 + 1] = n0a.y;
        nred[wave][g0 + 2] = n0a.z; nred[wave][g0 + 3] = n0a.w;
        nred[wave][g0 + 4] = n1a.x; nred[wave][g0 + 5] = n1a.y;
        nred[wave][g0 + 6] = n1a.z; nred[wave][g0 + 7] = n1a.w;
    }
    __syncthreads();
    size_t tokBase = (size_t)bh * 2048;
#pragma unroll
    for (int k = 0; k < 8; ++k) {
        int c = t + 256 * k;
        atomicAdd(&TOK[tokBase + c], red[0][c] + red[1][c] + red[2][c] + red[3][c]);
    }
    if (t < 64)
        atomicAdd(&NORM[bh * 64 + t], nred[0][t] + nred[1][t] + nred[2][t] + nred[3][t]);
}

// ---------------- attention over G=64 tokens (block per (b,h)) -------------
__global__ __launch_bounds__(256) void attn_kernel(
    const float* __restrict__ TOK, const float* __restrict__ NORM,
    const float* __restrict__ qw, const float* __restrict__ kw,
    const float* __restrict__ vw, float* __restrict__ OS)
{
    __shared__ float tokd[2048], qs[2048], ks[2048], vs[2048];
    int bh = blockIdx.x;
    int t = threadIdx.x;
#pragma unroll
    for (int i = 0; i < 2; ++i) {
        int f4v = t + 256 * i;
        float4 v = *(const float4*)(TOK + (size_t)bh * 2048 + f4v * 4);
        float inv = 1.0f / (NORM[bh * 64 + (f4v >> 3)] + 1e-5f);
        v.x *= inv; v.y *= inv; v.z *= inv; v.w *= inv;
        *(float4*)&tokd[f4v * 4] = v;
    }
    __syncthreads();
#pragma unroll
    for (int i = 0; i < 8; ++i) {
        int f = t + 256 * i;
        int g = f >> 5, d = f & 31;
        const float* tr = tokd + g * 32;
        float aq = 0.f, ak = 0.f, av = 0.f;
#pragma unroll
        for (int e = 0; e < 32; ++e) {
            float tv = tr[e];
            aq = fmaf(tv, qw[e * 32 + d], aq);
            ak = fmaf(tv, kw[e * 32 + d], ak);
            av = fmaf(tv, vw[e * 32 + d], av);
        }
        qs[f] = aq; ks[f] = ak; vs[f] = av;
    }
    __syncthreads();
    int g = t >> 2, sub = t & 3;
    float4 qv[8];
#pragma unroll
    for (int e4 = 0; e4 < 8; ++e4) qv[e4] = *(const float4*)(qs + g * 32 + e4 * 4);
    float p[16];
    float mx = -3.0e38f;
#pragma unroll
    for (int mm = 0; mm < 16; ++mm) {
        int mI = sub * 16 + mm;
        const float4* kr = (const float4*)(ks + mI * 32);
        float s = 0.f;
#pragma unroll
        for (int e4 = 0; e4 < 8; ++e4) {
            float4 kv = kr[e4];
            s = fmaf(qv[e4].x, kv.x, s); s = fmaf(qv[e4].y, kv.y, s);
            s = fmaf(qv[e4].z, kv.z, s); s = fmaf(qv[e4].w, kv.w, s);
        }
        s *= 0.17677669529663687f;   // 1/sqrt(32)
        p[mm] = s;
        mx = fmaxf(mx, s);
    }
    mx = fmaxf(mx, __shfl_xor(mx, 1));
    mx = fmaxf(mx, __shfl_xor(mx, 2));
    float lsum = 0.f;
#pragma unroll
    for (int mm = 0; mm < 16; ++mm) { p[mm] = expf(p[mm] - mx); lsum += p[mm]; }
    lsum += __shfl_xor(lsum, 1);
    lsum += __shfl_xor(lsum, 2);
    float inv = 1.0f / lsum;
    float4 oa[8];
#pragma unroll
    for (int d4 = 0; d4 < 8; ++d4) oa[d4] = make_float4(0.f, 0.f, 0.f, 0.f);
#pragma unroll
    for (int mm = 0; mm < 16; ++mm) {
        int mI = sub * 16 + mm;
        const float4* vr = (const float4*)(vs + mI * 32);
        float pm = p[mm];
#pragma unroll
        for (int d4 = 0; d4 < 8; ++d4) {
            float4 vv = vr[d4];
            oa[d4].x = fmaf(pm, vv.x, oa[d4].x);
            oa[d4].y = fmaf(pm, vv.y, oa[d4].y);
            oa[d4].z = fmaf(pm, vv.z, oa[d4].z);
            oa[d4].w = fmaf(pm, vv.w, oa[d4].w);
        }
    }
#pragma unroll
    for (int d4 = 0; d4 < 8; ++d4) {
        oa[d4].x += __shfl_xor(oa[d4].x, 1); oa[d4].x += __shfl_xor(oa[d4].x, 2);
        oa[d4].y += __shfl_xor(oa[d4].y, 1); oa[d4].y += __shfl_xor(oa[d4].y, 2);
        oa[d4].z += __shfl_xor(oa[d4].z, 1); oa[d4].z += __shfl_xor(oa[d4].z, 2);
        oa[d4].w += __shfl_xor(oa[d4].w, 1); oa[d4].w += __shfl_xor(oa[d4].w, 2);
    }
    float4 r0 = oa[sub * 2], r1 = oa[sub * 2 + 1];
    r0.x *= inv; r0.y *= inv; r0.z *= inv; r0.w *= inv;
    r1.x *= inv; r1.y *= inv; r1.z *= inv; r1.w *= inv;
    *(float4*)(OS + (size_t)bh * 2048 + g * 32 + sub * 8)     = r0;
    *(float4*)(OS + (size_t)bh * 2048 + g * 32 + sub * 8 + 4) = r1;
}

// ---------------- deslice: out_x = einsum(out_slice, sw) -> bf16 -----------
__global__ __launch_bounds__(256) void deslice_kernel(
    const float* __restrict__ OS, const u16* __restrict__ SW, u16* __restrict__ OX)
{
    __shared__ float swt[8 * 16 * 64];   // [hd][mm][g]
    int blk = blockIdx.x;
    int b = blk >> 10, n0 = (blk & 1023) * 16;
    int t = threadIdx.x;
    int hd = t >> 5, d = t & 31;
#pragma unroll
    for (int i = 0; i < 8; ++i) {
        int f4v = t + 256 * i;
        int hd2 = f4v >> 8, mm = (f4v >> 4) & 15, g4 = f4v & 15;
        ushort4 u = *(const ushort4*)(SW + (((size_t)(b * 8 + hd2)) * NB + n0 + mm) * 64 + g4 * 4);
        *(float4*)&swt[(hd2 * 16 + mm) * 64 + g4 * 4] = dec4(u);
    }
    __syncthreads();
    float acc[16];
#pragma unroll
    for (int mm = 0; mm < 16; ++mm) acc[mm] = 0.f;
    const float* osb = OS + ((size_t)(b * 8 + hd)) * 2048 + d;
#pragma unroll 4
    for (int g4 = 0; g4 < 16; ++g4) {
        float o0 = osb[(g4 * 4 + 0) * 32], o1 = osb[(g4 * 4 + 1) * 32];
        float o2 = osb[(g4 * 4 + 2) * 32], o3 = osb[(g4 * 4 + 3) * 32];
        const float* swp = swt + hd * 1024 + g4 * 4;
#pragma unroll
        for (int mm = 0; mm < 16; ++mm) {
            float4 sv = *(const float4*)(swp + mm * 64);
            acc[mm] = fmaf(o0, sv.x, fmaf(o1, sv.y, fmaf(o2, sv.z, fmaf(o3, sv.w, acc[mm]))));
        }
    }
#pragma unroll
    for (int mm = 0; mm < 16; ++mm)
        OX[((size_t)b * NB + n0 + mm) * 256 + t] = f2bf(acc[mm]);
}

// ---------------- head stage 2: out = hid @ head_w2 + b2 -------------------
__global__ __launch_bounds__(256) void head2_kernel(
    const u16* __restrict__ HID, const float* __restrict__ w2,
    const float* __restrict__ b2, const void* tmp, void* __restrict__ OUT)
{
    int isbf = (((const u16*)tmp)[0] != 0);
    int lane = threadIdx.x & 63;
    size_t m = (size_t)blockIdx.x * 4 + (threadIdx.x >> 6);
    const float4 hv = dec4(*(const ushort4*)(HID + m * 256 + lane * 4));
    float4 a = make_float4(0.f, 0.f, 0.f, 0.f);
    float hcomp[4] = {hv.x, hv.y, hv.z, hv.w};
#pragma unroll
    for (int i = 0; i < 4; ++i) {
        const float4 wv = *(const float4*)(w2 + (lane * 4 + i) * 4);
        float h = hcomp[i];
        a.x = fmaf(h, wv.x, a.x); a.y = fmaf(h, wv.y, a.y);
        a.z = fmaf(h, wv.z, a.z); a.w = fmaf(h, wv.w, a.w);
    }
#pragma unroll
    for (int o = 32; o; o >>= 1) {
        a.x += __shfl_xor(a.x, o); a.y += __shfl_xor(a.y, o);
        a.z += __shfl_xor(a.z, o); a.w += __shfl_xor(a.w, o);
    }
    if (lane == 0) {
        float o0 = a.x + b2[0], o1 = a.y + b2[1], o2 = a.z + b2[2], o3 = a.w + b2[3];
        if (isbf) {
            ushort4 r; r.x = f2bf(o0); r.y = f2bf(o1); r.z = f2bf(o2); r.w = f2bf(o3);
            *(ushort4*)((u16*)OUT + m * 4) = r;
        } else {
            *(float4*)((float*)OUT + m * 4) = make_float4(o0, o1, o2, o3);
        }
    }
}

// ---------------------------------------------------------------------------
extern "C" void kernel_launch(void* const* d_in, const int* in_sizes, int n_in,
                              void* d_out, int out_size, void* d_ws, size_t ws_size,
                              hipStream_t stream)
{
    const void* x = d_in[0];      const void* fx = d_in[1];
    const void* pre_w1 = d_in[2]; const void* pre_b1 = d_in[3];
    const void* pre_w2 = d_in[4]; const void* pre_b2 = d_in[5];
    const void* placeholder = d_in[6];
    const void* ln1_g = d_in[7];  const void* ln1_b = d_in[8];
    const void* px_w = d_in[9];   const void* px_b = d_in[10];
    const void* pfx_w = d_in[11]; const void* pfx_b = d_in[12];
    const void* slice_w = d_in[13]; const void* slice_b = d_in[14];
    const void* temp = d_in[15];
    const void* q_w = d_in[16];   const void* k_w = d_in[17]; const void* v_w = d_in[18];
    const void* out_w = d_in[19]; const void* out_b = d_in[20];
    const void* ln2_g = d_in[21]; const void* ln2_b = d_in[22];
    const void* mlp_w1 = d_in[23]; const void* mlp_b1 = d_in[24];
    const void* mlp_w2 = d_in[25]; const void* mlp_b2 = d_in[26];
    const void* ln3_g = d_in[27]; const void* ln3_b = d_in[28];
    const void* head_w1 = d_in[29]; const void* head_b1 = d_in[30];
    const void* head_w2 = d_in[31]; const void* head_b2 = d_in[32];

    float* ws = (float*)d_ws;
    float* H     = ws + F_H;
    float* TOKp  = ws + F_TOK;
    float* NORMp = ws + F_NORM;
    float* OSp   = ws + F_OS;
    float* BIAS  = ws + F_BIAS;
    float* P     = ws + F_PARAMS;
    u16*   U     = (u16*)(ws + F_BF);
    u16*   WT    = U + U_WT;
    u16*   Yb    = U + U_Y;
    u16*   XMb   = U + U_XM;
    u16*   FMb   = U + U_FM;
    u16*   SWb   = U + U_SW;
    u16*   HIDb  = U + U_XM;   // [M,512] spans XM+FM (free before layer loop)

    cvt_kernel<<<910, 256, 0, stream>>>(x, fx, pre_w1, pre_b1, ln1_g, ln1_b,
        ln2_g, ln2_b, ln3_g, ln3_b, slice_w, slice_b, temp, q_w, k_w, v_w,
        head_w2, head_b2, P);
    prep_kernel<<<7195, 256, 0, stream>>>(pre_w2, head_w1, px_w, pfx_w, out_w,
        mlp_w1, mlp_w2, pre_b2, placeholder, px_b, pfx_b, out_b, mlp_b1, mlp_b2,
        head_b1, temp, WT, BIAS);
    pre1_kernel<<<65536, 256, 0, stream>>>(P, HIDb);

    dim3 gg(256, 2);
    gemm_mfma<512, 0><<<gg, 256, 0, stream>>>(HIDb, WT + WT_PRE2, BIAS + B_PB2C, H, nullptr);

    for (int i = 0; i < 5; ++i) {
        ln_kernel<<<8192, 256, 0, stream>>>(H, P + P_LN1G + i * 256, P + P_LN1B + i * 256, Yb);
        gemm_mfma<256, 2><<<gg, 256, 0, stream>>>(Yb, WT + WT_PX  + i * 65536, BIAS + B_PXB  + i * 256, nullptr, XMb);
        gemm_mfma<256, 2><<<gg, 256, 0, stream>>>(Yb, WT + WT_PFX + i * 65536, BIAS + B_PFXB + i * 256, nullptr, FMb);
        slice_kernel<<<65536, 256, 0, stream>>>(XMb, P + P_SLW + i * 2048, P + P_SLB + i * 64, P + P_TEMP + i * 8, SWb);
        hipMemsetAsync(TOKp, 0, (size_t)33792 * 4, stream);
        tok_kernel<<<1024, 256, 0, stream>>>(FMb, SWb, TOKp, NORMp);
        attn_kernel<<<16, 256, 0, stream>>>(TOKp, NORMp, P + P_QW + i * 1024, P + P_KW + i * 1024, P + P_VW + i * 1024, OSp);
        deslice_kernel<<<2048, 256, 0, stream>>>(OSp, SWb, Yb);
        gemm_mfma<256, 1><<<gg, 256, 0, stream>>>(Yb, WT + WT_OUT + i * 65536, BIAS + B_OUTB + i * 256, H, nullptr);
        ln_kernel<<<8192, 256, 0, stream>>>(H, P + P_LN2G + i * 256, P + P_LN2B + i * 256, Yb);
        gemm_mfma<256, 3><<<gg, 256, 0, stream>>>(Yb,  WT + WT_MLP1 + i * 65536, BIAS + B_M1B + i * 256, nullptr, XMb);
        gemm_mfma<256, 1><<<gg, 256, 0, stream>>>(XMb, WT + WT_MLP2 + i * 65536, BIAS + B_M2B + i * 256, H, nullptr);
    }

    ln_kernel<<<8192, 256, 0, stream>>>(H, P + P_LN3G, P + P_LN3B, Yb);
    gemm_mfma<256, 3><<<gg, 256, 0, stream>>>(Yb, WT + WT_HEAD1, BIAS + B_HB1, nullptr, XMb);
    head2_kernel<<<8192, 256, 0, stream>>>(XMb, P + P_HW2, P + P_HB2, temp, d_out);
}

// Round 4
// 1265.140 us; speedup vs baseline: 2.4706x; 1.3619x over previous
//
#include <hip/hip_runtime.h>

// ---------------------------------------------------------------------------
// Transolver forward, MI355X. Round 4: fold px_w@slice_w into one [256,512]
// GEMM with fused temp-scale+softmax epilogue writing SW directly
// (removes slice_kernel 547us + 5 px GEMMs). Rest unchanged from passing R3.
// ---------------------------------------------------------------------------

#define MTOK 32768   // B*N
#define NB   16384   // N

typedef unsigned short u16;
using short8 = __attribute__((ext_vector_type(8))) short;
using f4     = __attribute__((ext_vector_type(4))) float;

__device__ __forceinline__ float bfu(u16 u) {
    return __uint_as_float(((unsigned)u) << 16);
}
__device__ __forceinline__ u16 f2bf(float f) {
    unsigned u = __float_as_uint(f);
    u += 0x7FFFu + ((u >> 16) & 1u);   // round-to-nearest-even
    return (u16)(u >> 16);
}
__device__ __forceinline__ float ldf(const void* p, int i, int isbf) {
    return isbf ? bfu(((const u16*)p)[i]) : ((const float*)p)[i];
}
__device__ __forceinline__ float4 dec4(ushort4 u) {
    return make_float4(bfu(u.x), bfu(u.y), bfu(u.z), bfu(u.w));
}
__device__ __forceinline__ float gelu_f(float x) {
    return 0.5f * x * (1.0f + erff(x * 0.7071067811865475f));
}

// ---------------- workspace layout -----------------------------------------
// fp32 region (float offsets)
#define F_H      ((size_t)0)          // fp32 residual [32768,256]
#define F_TOK    ((size_t)8388608)
#define F_NORM   ((size_t)8421376)
#define F_OS     ((size_t)8422400)
#define F_BIAS   ((size_t)8455168)    // fp32 biases
#define F_PARAMS ((size_t)8463360)    // fp32 small params (232836)
#define F_BF     ((size_t)8696196)    // u16 region base (x4 = 16B aligned)
// bias-internal (floats, rel to F_BIAS)
#define B_PB2C 0
#define B_PFXB 256
#define B_OUTB 1536
#define B_M1B  2816
#define B_M2B  4096
#define B_HB1  5376
#define B_SL   5632     // folded slice bias [5][512]
#define B_END  8192
// u16 region offsets
#define U_WT     ((size_t)0)
#define WT_PRE2  0                   // [256][512]
#define WT_HEAD1 131072              // [256][256]
#define WT_PXSL  196608              // 5 x [512][256]  (folded px@slice)
#define WT_PFX   851968              // 5 x [256][256]
#define WT_OUT   1179648
#define WT_MLP1  1507328
#define WT_MLP2  1835008
#define WT_END   2162688
#define U_Y   ((size_t)2162688)      // [32768,256] bf16
#define U_XM  ((size_t)10551296)     // [32768,256]; +FM doubles as HID [32768,512]
#define U_FM  ((size_t)18939904)
#define U_SW  ((size_t)27328512)     // [16,16384,64]
// total ws: 8696196*4 + 44105728*2 = 122,996,240 B (~117.3 MB)

// params-internal offsets (floats, rel to F_PARAMS)
#define P_X    0
#define P_FX   65536
#define P_W1   196608
#define P_B1   199680
#define P_LN1G 200192
#define P_LN1B 201472
#define P_LN2G 202752
#define P_LN2B 204032
#define P_LN3G 205312
#define P_LN3B 205568
#define P_SLW  205824
#define P_SLB  216064
#define P_TEMP 216384
#define P_QW   216448
#define P_KW   221568
#define P_VW   226688
#define P_HW2  231808
#define P_HB2  232832
#define P_END  232836

// ---------------- cvt: small params -> fp32 params region ------------------
__global__ __launch_bounds__(256) void cvt_kernel(
    const void* x, const void* fx, const void* w1, const void* b1,
    const void* l1g, const void* l1b, const void* l2g, const void* l2b,
    const void* l3g, const void* l3b, const void* slw, const void* slb,
    const void* tmp, const void* qw, const void* kw, const void* vw,
    const void* hw2, const void* hb2, float* __restrict__ P)
{
    int isbf = (((const u16*)tmp)[0] != 0);
    int idx = blockIdx.x * 256 + threadIdx.x;
    const void* s; int o;
    if      (idx < 65536)  { s = x;   o = idx; }
    else if (idx < 196608) { s = fx;  o = idx - 65536; }
    else if (idx < 199680) { s = w1;  o = idx - 196608; }
    else if (idx < 200192) { s = b1;  o = idx - 199680; }
    else if (idx < 201472) { s = l1g; o = idx - 200192; }
    else if (idx < 202752) { s = l1b; o = idx - 201472; }
    else if (idx < 204032) { s = l2g; o = idx - 202752; }
    else if (idx < 205312) { s = l2b; o = idx - 204032; }
    else if (idx < 205568) { s = l3g; o = idx - 205312; }
    else if (idx < 205824) { s = l3b; o = idx - 205568; }
    else if (idx < 216064) { s = slw; o = idx - 205824; }
    else if (idx < 216384) { s = slb; o = idx - 216064; }
    else if (idx < 216424) { s = tmp; o = idx - 216384; }
    else if (idx < 216448) { return; }
    else if (idx < 221568) { s = qw;  o = idx - 216448; }
    else if (idx < 226688) { s = kw;  o = idx - 221568; }
    else if (idx < 231808) { s = vw;  o = idx - 226688; }
    else if (idx < 232832) { s = hw2; o = idx - 231808; }
    else if (idx < 232836) { s = hb2; o = idx - 232832; }
    else return;
    P[idx] = ldf(s, o, isbf);
}

// ---------------- prep: weights -> bf16 W^T [N][K]; fold px@slice ----------
__global__ __launch_bounds__(256) void prep_kernel(
    const void* pre_w2, const void* head_w1, const void* px_w, const void* pfx_w,
    const void* out_w, const void* mlp_w1, const void* mlp_w2, const void* pre_b2,
    const void* placeholder, const void* px_b, const void* pfx_b, const void* out_b,
    const void* mlp_b1, const void* mlp_b2, const void* head_b1,
    const void* slw, const void* slb, const void* tmp,
    u16* __restrict__ WT, float* __restrict__ BIAS)
{
    int isbf = (((const u16*)tmp)[0] != 0);
    int idx = blockIdx.x * 256 + threadIdx.x;
    if (idx < 131072) {                       // pre_w2 [512,256] -> [256][512]
        int n = idx >> 9, k = idx & 511;
        WT[idx] = f2bf(ldf(pre_w2, k * 256 + n, isbf));
    } else if (idx < WT_PXSL) {               // head_w1 [256][256]
        int f = idx - 131072;
        int n = f >> 8, k = f & 255;
        WT[idx] = f2bf(ldf(head_w1, k * 256 + n, isbf));
    } else if (idx < WT_PFX) {                // folded pxsl: 5 x [512][256]
        int f = idx - WT_PXSL;
        int i = f / 131072, r = f % 131072;
        int n = r >> 8, k = r & 255;
        int h = n >> 6, g = n & 63;
        float a = 0.f;
#pragma unroll
        for (int d = 0; d < 32; ++d)
            a = fmaf(ldf(px_w, i * 65536 + k * 256 + h * 32 + d, isbf),
                     ldf(slw, i * 2048 + d * 64 + g, isbf), a);
        WT[idx] = f2bf(a);
    } else if (idx < WT_END) {                // pfx/out/mlp1/mlp2: 20 [256,256]
        int f = idx - WT_PFX;
        int mat = f >> 16;
        int r = f & 65535;
        const void* s; int off = (mat % 5) * 65536;
        if      (mat < 5)  s = pfx_w;
        else if (mat < 10) s = out_w;
        else if (mat < 15) s = mlp_w1;
        else               s = mlp_w2;
        int n = r >> 8, k = r & 255;
        WT[idx] = f2bf(ldf(s, off + k * 256 + n, isbf));
    } else if (idx < WT_END + 256) {          // pb2c = pre_b2 + placeholder
        int c = idx - WT_END;
        BIAS[B_PB2C + c] = ldf(pre_b2, c, isbf) + ldf(placeholder, c, isbf);
    } else if (idx < WT_END + B_SL) {         // plain fp32 biases
        int o = idx - (WT_END + 256);
        float v;
        if      (o < 1280) v = ldf(pfx_b,  o,        isbf);
        else if (o < 2560) v = ldf(out_b,  o - 1280, isbf);
        else if (o < 3840) v = ldf(mlp_b1, o - 2560, isbf);
        else if (o < 5120) v = ldf(mlp_b2, o - 3840, isbf);
        else               v = ldf(head_b1, o - 5120, isbf);
        BIAS[B_PFXB + o] = v;
    } else if (idx < WT_END + B_END) {        // folded slice bias [5][512]
        int o = idx - (WT_END + B_SL);
        int i = o >> 9, n = o & 511;
        int h = n >> 6, g = n & 63;
        float a = ldf(slb, i * 64 + g, isbf);
#pragma unroll
        for (int d = 0; d < 32; ++d)
            a = fmaf(ldf(px_b, i * 256 + h * 32 + d, isbf),
                     ldf(slw, i * 2048 + d * 64 + g, isbf), a);
        BIAS[B_SL + o] = a;
    }
}

// ---------------- preprocess stage 1: gelu(in6 @ pre_w1 + b1) -> bf16 ------
__global__ __launch_bounds__(256) void pre1_kernel(
    const float* __restrict__ P, u16* __restrict__ HID)
{
    int idx = blockIdx.x * 256 + threadIdx.x;   // < M*512
    int m = idx >> 9, j = idx & 511;
    const float* xx = P + P_X;
    const float* ff = P + P_FX;
    const float* w1 = P + P_W1;
    float a = P[P_B1 + j];
    a = fmaf(xx[m * 2 + 0], w1[0 * 512 + j], a);
    a = fmaf(xx[m * 2 + 1], w1[1 * 512 + j], a);
    a = fmaf(ff[m * 4 + 0], w1[2 * 512 + j], a);
    a = fmaf(ff[m * 4 + 1], w1[3 * 512 + j], a);
    a = fmaf(ff[m * 4 + 2], w1[4 * 512 + j], a);
    a = fmaf(ff[m * 4 + 3], w1[5 * 512 + j], a);
    HID[idx] = f2bf(gelu_f(a));
}

// ---------------- MFMA GEMM: C[M,256] = f(A[M,KK]bf16 @ W + b) -------------
// Wt bf16 [N][KK] (N-major). Block: 128x128 tile, 4 waves 2x2 of 64x64.
// OMODE: 0 fp32 store, 1 fp32 +=residual, 2 bf16 store, 3 gelu->bf16 store.
template <int KK, int OMODE>
__global__ __launch_bounds__(256, 2) void gemm_mfma(
    const u16* __restrict__ A, const u16* __restrict__ Wt,
    const float* __restrict__ bias, float* __restrict__ C, u16* __restrict__ Cb)
{
    __shared__ u16 As[128 * 72];
    __shared__ u16 Bs[128 * 72];
    const int t = threadIdx.x;
    const int wave = t >> 6, lane = t & 63;
    const int quad = lane >> 4, l15 = lane & 15;
    const int m0 = blockIdx.x * 128;
    const int n0 = blockIdx.y * 128;
    const int wm = (wave & 1) * 64, wn = (wave >> 1) * 64;
    f4 acc[4][4];
#pragma unroll
    for (int i = 0; i < 4; ++i)
#pragma unroll
        for (int j = 0; j < 4; ++j)
            acc[i][j] = (f4){0.f, 0.f, 0.f, 0.f};

    for (int kc = 0; kc < KK; kc += 64) {
        if (kc) __syncthreads();
#pragma unroll
        for (int i = 0; i < 4; ++i) {
            int c = t + 256 * i;
            int row = c >> 3, col = (c & 7) * 8;
            *(ulonglong2*)(As + row * 72 + col) =
                *(const ulonglong2*)(A + (size_t)(m0 + row) * KK + kc + col);
            *(ulonglong2*)(Bs + row * 72 + col) =
                *(const ulonglong2*)(Wt + (size_t)(n0 + row) * KK + kc + col);
        }
        __syncthreads();
#pragma unroll
        for (int k32 = 0; k32 < 64; k32 += 32) {
            short8 a[4], b[4];
#pragma unroll
            for (int i = 0; i < 4; ++i)
                a[i] = *(const short8*)(As + (wm + i * 16 + l15) * 72 + k32 + quad * 8);
#pragma unroll
            for (int j = 0; j < 4; ++j)
                b[j] = *(const short8*)(Bs + (wn + j * 16 + l15) * 72 + k32 + quad * 8);
#pragma unroll
            for (int i = 0; i < 4; ++i)
#pragma unroll
                for (int j = 0; j < 4; ++j)
                    acc[i][j] = __builtin_amdgcn_mfma_f32_16x16x32_bf16(
                        a[i], b[j], acc[i][j], 0, 0, 0);
        }
    }
#pragma unroll
    for (int j = 0; j < 4; ++j) {
        int cj = n0 + wn + j * 16 + l15;
        float bj = bias[cj];
#pragma unroll
        for (int i = 0; i < 4; ++i) {
            int rbase = m0 + wm + i * 16 + quad * 4;
#pragma unroll
            for (int r = 0; r < 4; ++r) {
                float v = acc[i][j][r] + bj;
                size_t off = (size_t)(rbase + r) * 256 + cj;
                if (OMODE == 3) v = gelu_f(v);
                if (OMODE == 1) v += C[off];
                if (OMODE >= 2) Cb[off] = f2bf(v);
                else            C[off] = v;
            }
        }
    }
}

// ---------------- fused px@slice GEMM + temp-softmax -> SW bf16 ------------
// A: Y bf16 [32768,256]; Wt: folded [512][256]; bsl: folded bias [512];
// tempv: [8]. Output SW[(b*8+h)*NB+n]*64+g. Grid (256, 4).
__global__ __launch_bounds__(256, 2) void gemm_slice(
    const u16* __restrict__ A, const u16* __restrict__ Wt,
    const float* __restrict__ bsl, const float* __restrict__ tempv,
    u16* __restrict__ SW)
{
    __shared__ u16 As[128 * 72];
    __shared__ u16 Bs[128 * 72];
    const int t = threadIdx.x;
    const int wave = t >> 6, lane = t & 63;
    const int quad = lane >> 4, l15 = lane & 15;
    const int m0 = blockIdx.x * 128;
    const int n0 = blockIdx.y * 128;
    const int wm = (wave & 1) * 64, wn = (wave >> 1) * 64;
    f4 acc[4][4];
#pragma unroll
    for (int i = 0; i < 4; ++i)
#pragma unroll
        for (int j = 0; j < 4; ++j)
            acc[i][j] = (f4){0.f, 0.f, 0.f, 0.f};

    for (int kc = 0; kc < 256; kc += 64) {
        if (kc) __syncthreads();
#pragma unroll
        for (int i = 0; i < 4; ++i) {
            int c = t + 256 * i;
            int row = c >> 3, col = (c & 7) * 8;
            *(ulonglong2*)(As + row * 72 + col) =
                *(const ulonglong2*)(A + (size_t)(m0 + row) * 256 + kc + col);
            *(ulonglong2*)(Bs + row * 72 + col) =
                *(const ulonglong2*)(Wt + (size_t)(n0 + row) * 256 + kc + col);
        }
        __syncthreads();
#pragma unroll
        for (int k32 = 0; k32 < 64; k32 += 32) {
            short8 a[4], b[4];
#pragma unroll
            for (int i = 0; i < 4; ++i)
                a[i] = *(const short8*)(As + (wm + i * 16 + l15) * 72 + k32 + quad * 8);
#pragma unroll
            for (int j = 0; j < 4; ++j)
                b[j] = *(const short8*)(Bs + (wn + j * 16 + l15) * 72 + k32 + quad * 8);
#pragma unroll
            for (int i = 0; i < 4; ++i)
#pragma unroll
                for (int j = 0; j < 4; ++j)
                    acc[i][j] = __builtin_amdgcn_mfma_f32_16x16x32_bf16(
                        a[i], b[j], acc[i][j], 0, 0, 0);
        }
    }
    // epilogue: logits -> /temp -> softmax over g (64 cols of this wave)
    const int h = (n0 + wn) >> 6;          // head index
    const float itemp = 1.0f / tempv[h];
    float bj[4];
#pragma unroll
    for (int j = 0; j < 4; ++j) bj[j] = bsl[n0 + wn + j * 16 + l15];
#pragma unroll
    for (int i = 0; i < 4; ++i) {
#pragma unroll
        for (int r = 0; r < 4; ++r) {
            float v[4];
            float mx = -3.0e38f;
#pragma unroll
            for (int j = 0; j < 4; ++j) {
                v[j] = (acc[i][j][r] + bj[j]) * itemp;
                mx = fmaxf(mx, v[j]);
            }
#pragma unroll
            for (int o = 1; o < 16; o <<= 1) mx = fmaxf(mx, __shfl_xor(mx, o));
            float s = 0.f;
#pragma unroll
            for (int j = 0; j < 4; ++j) { v[j] = expf(v[j] - mx); s += v[j]; }
#pragma unroll
            for (int o = 1; o < 16; o <<= 1) s += __shfl_xor(s, o);
            float inv = 1.0f / s;
            int m = m0 + wm + i * 16 + quad * 4 + r;
            int b = m >> 14, n = m & 16383;
            size_t base = (((size_t)(b * 8 + h)) * NB + n) * 64;
#pragma unroll
            for (int j = 0; j < 4; ++j)
                SW[base + j * 16 + l15] = f2bf(v[j] * inv);
        }
    }
}

// ---------------- LayerNorm: fp32 in -> bf16 out (wave per token) ----------
__global__ __launch_bounds__(256) void ln_kernel(
    const float* __restrict__ X, const float* __restrict__ g,
    const float* __restrict__ b, u16* __restrict__ Y)
{
    int lane = threadIdx.x & 63;
    size_t m = (size_t)blockIdx.x * 4 + (threadIdx.x >> 6);
    const float4 x4 = *(const float4*)(X + m * 256 + lane * 4);
    float s = x4.x + x4.y + x4.z + x4.w;
    float q = x4.x * x4.x + x4.y * x4.y + x4.z * x4.z + x4.w * x4.w;
#pragma unroll
    for (int o = 32; o; o >>= 1) { s += __shfl_xor(s, o); q += __shfl_xor(q, o); }
    float mean = s * (1.0f / 256.0f);
    float var = q * (1.0f / 256.0f) - mean * mean;
    float inv = 1.0f / sqrtf(var + 1e-5f);
    const float4 g4 = *(const float4*)(g + lane * 4);
    const float4 b4 = *(const float4*)(b + lane * 4);
    ushort4 y;
    y.x = f2bf((x4.x - mean) * inv * g4.x + b4.x);
    y.y = f2bf((x4.y - mean) * inv * g4.y + b4.y);
    y.z = f2bf((x4.z - mean) * inv * g4.z + b4.z);
    y.w = f2bf((x4.w - mean) * inv * g4.w + b4.w);
    *(ushort4*)(Y + m * 256 + lane * 4) = y;
}

// ---------------- tok reduction over N (+ norm) ----------------------------
__global__ __launch_bounds__(256) void tok_kernel(
    const u16* __restrict__ FM, const u16* __restrict__ SW,
    float* __restrict__ TOK, float* __restrict__ NORM)
{
    int bh = blockIdx.x >> 6, chunk = blockIdx.x & 63;
    int b = bh >> 3, hd = bh & 7;
    int t = threadIdx.x, wave = t >> 6, lane = t & 63;
    int g0 = (lane >> 3) * 8, d0 = (lane & 7) * 4;
    float4 acc[8];
#pragma unroll
    for (int gi = 0; gi < 8; ++gi) acc[gi] = make_float4(0.f, 0.f, 0.f, 0.f);
    float4 n0a = make_float4(0.f, 0.f, 0.f, 0.f);
    float4 n1a = make_float4(0.f, 0.f, 0.f, 0.f);
    int nbase = chunk * 256 + wave * 64;
    const u16* fmB = FM + ((size_t)b * NB + nbase) * 256 + hd * 32 + d0;
    const u16* swB = SW + ((size_t)bh * NB + nbase) * 64 + g0;
    for (int j = 0; j < 64; ++j) {
        float4 f4v = dec4(*(const ushort4*)(fmB + (size_t)j * 256));
        float4 s0 = dec4(*(const ushort4*)(swB + (size_t)j * 64));
        float4 s1 = dec4(*(const ushort4*)(swB + (size_t)j * 64 + 4));
#define TOKACC(gi, sv)                                            \
        acc[gi].x = fmaf(f4v.x, sv, acc[gi].x);                   \
        acc[gi].y = fmaf(f4v.y, sv, acc[gi].y);                   \
        acc[gi].z = fmaf(f4v.z, sv, acc[gi].z);                   \
        acc[gi].w = fmaf(f4v.w, sv, acc[gi].w);
        TOKACC(0, s0.x) TOKACC(1, s0.y) TOKACC(2, s0.z) TOKACC(3, s0.w)
        TOKACC(4, s1.x) TOKACC(5, s1.y) TOKACC(6, s1.z) TOKACC(7, s1.w)
#undef TOKACC
        n0a.x += s0.x; n0a.y += s0.y; n0a.z += s0.z; n0a.w += s0.w;
        n1a.x += s1.x; n1a.y += s1.y; n1a.z += s1.z; n1a.w += s1.w;
    }
    __shared__ float red[4][2048];
    __shared__ float nred[4][64];
#pragma unroll
    for (int gi = 0; gi < 8; ++gi)
        *(float4*)&red[wave][(g0 + gi) * 32 + d0] = acc[gi];
    if ((lane & 7) == 0) {
        nred[wave][g0 + 0] = n0a.x; nred[wave][g0 + 1] = n0a.y;
        nred[wave][g0 + 2] = n0a.z; nred[wave][g0 + 3] = n0a.w;
        nred[wave][g0 + 4] = n1a.x; nred[wave][g0 + 5] = n1a.y;
        nred[wave][g0 + 6] = n1a.z; nred[wave][g0 + 7] = n1a.w;
    }
    __syncthreads();
    size_t tokBase = (size_t)bh * 2048;
#pragma unroll
    for (int k = 0; k < 8; ++k) {
        int c = t + 256 * k;
        atomicAdd(&TOK[tokBase + c], red[0][c] + red[1][c] + red[2][c] + red[3][c]);
    }
    if (t < 64)
        atomicAdd(&NORM[bh * 64 + t], nred[0][t] + nred[1][t] + nred[2][t] + nred[3][t]);
}

// ---------------- attention over G=64 tokens (block per (b,h)) -------------
__global__ __launch_bounds__(256) void attn_kernel(
    const float* __restrict__ TOK, const float* __restrict__ NORM,
    const float* __restrict__ qw, const float* __restrict__ kw,
    const float* __restrict__ vw, float* __restrict__ OS)
{
    __shared__ float tokd[2048], qs[2048], ks[2048], vs[2048];
    int bh = blockIdx.x;
    int t = threadIdx.x;
#pragma unroll
    for (int i = 0; i < 2; ++i) {
        int f4v = t + 256 * i;
        float4 v = *(const float4*)(TOK + (size_t)bh * 2048 + f4v * 4);
        float inv = 1.0f / (NORM[bh * 64 + (f4v >> 3)] + 1e-5f);
        v.x *= inv; v.y *= inv; v.z *= inv; v.w *= inv;
        *(float4*)&tokd[f4v * 4] = v;
    }
    __syncthreads();
#pragma unroll
    for (int i = 0; i < 8; ++i) {
        int f = t + 256 * i;
        int g = f >> 5, d = f & 31;
        const float* tr = tokd + g * 32;
        float aq = 0.f, ak = 0.f, av = 0.f;
#pragma unroll
        for (int e = 0; e < 32; ++e) {
            float tv = tr[e];
            aq = fmaf(tv, qw[e * 32 + d], aq);
            ak = fmaf(tv, kw[e * 32 + d], ak);
            av = fmaf(tv, vw[e * 32 + d], av);
        }
        qs[f] = aq; ks[f] = ak; vs[f] = av;
    }
    __syncthreads();
    int g = t >> 2, sub = t & 3;
    float4 qv[8];
#pragma unroll
    for (int e4 = 0; e4 < 8; ++e4) qv[e4] = *(const float4*)(qs + g * 32 + e4 * 4);
    float p[16];
    float mx = -3.0e38f;
#pragma unroll
    for (int mm = 0; mm < 16; ++mm) {
        int mI = sub * 16 + mm;
        const float4* kr = (const float4*)(ks + mI * 32);
        float s = 0.f;
#pragma unroll
        for (int e4 = 0; e4 < 8; ++e4) {
            float4 kv = kr[e4];
            s = fmaf(qv[e4].x, kv.x, s); s = fmaf(qv[e4].y, kv.y, s);
            s = fmaf(qv[e4].z, kv.z, s); s = fmaf(qv[e4].w, kv.w, s);
        }
        s *= 0.17677669529663687f;   // 1/sqrt(32)
        p[mm] = s;
        mx = fmaxf(mx, s);
    }
    mx = fmaxf(mx, __shfl_xor(mx, 1));
    mx = fmaxf(mx, __shfl_xor(mx, 2));
    float lsum = 0.f;
#pragma unroll
    for (int mm = 0; mm < 16; ++mm) { p[mm] = expf(p[mm] - mx); lsum += p[mm]; }
    lsum += __shfl_xor(lsum, 1);
    lsum += __shfl_xor(lsum, 2);
    float inv = 1.0f / lsum;
    float4 oa[8];
#pragma unroll
    for (int d4 = 0; d4 < 8; ++d4) oa[d4] = make_float4(0.f, 0.f, 0.f, 0.f);
#pragma unroll
    for (int mm = 0; mm < 16; ++mm) {
        int mI = sub * 16 + mm;
        const float4* vr = (const float4*)(vs + mI * 32);
        float pm = p[mm];
#pragma unroll
        for (int d4 = 0; d4 < 8; ++d4) {
            float4 vv = vr[d4];
            oa[d4].x = fmaf(pm, vv.x, oa[d4].x);
            oa[d4].y = fmaf(pm, vv.y, oa[d4].y);
            oa[d4].z = fmaf(pm, vv.z, oa[d4].z);
            oa[d4].w = fmaf(pm, vv.w, oa[d4].w);
        }
    }
#pragma unroll
    for (int d4 = 0; d4 < 8; ++d4) {
        oa[d4].x += __shfl_xor(oa[d4].x, 1); oa[d4].x += __shfl_xor(oa[d4].x, 2);
        oa[d4].y += __shfl_xor(oa[d4].y, 1); oa[d4].y += __shfl_xor(oa[d4].y, 2);
        oa[d4].z += __shfl_xor(oa[d4].z, 1); oa[d4].z += __shfl_xor(oa[d4].z, 2);
        oa[d4].w += __shfl_xor(oa[d4].w, 1); oa[d4].w += __shfl_xor(oa[d4].w, 2);
    }
    float4 r0 = oa[sub * 2], r1 = oa[sub * 2 + 1];
    r0.x *= inv; r0.y *= inv; r0.z *= inv; r0.w *= inv;
    r1.x *= inv; r1.y *= inv; r1.z *= inv; r1.w *= inv;
    *(float4*)(OS + (size_t)bh * 2048 + g * 32 + sub * 8)     = r0;
    *(float4*)(OS + (size_t)bh * 2048 + g * 32 + sub * 8 + 4) = r1;
}

// ---------------- deslice: out_x = einsum(out_slice, sw) -> bf16 -----------
__global__ __launch_bounds__(256) void deslice_kernel(
    const float* __restrict__ OS, const u16* __restrict__ SW, u16* __restrict__ OX)
{
    __shared__ float swt[8 * 16 * 64];   // [hd][mm][g]
    int blk = blockIdx.x;
    int b = blk >> 10, n0 = (blk & 1023) * 16;
    int t = threadIdx.x;
    int hd = t >> 5, d = t & 31;
#pragma unroll
    for (int i = 0; i < 8; ++i) {
        int f4v = t + 256 * i;
        int hd2 = f4v >> 8, mm = (f4v >> 4) & 15, g4 = f4v & 15;
        ushort4 u = *(const ushort4*)(SW + (((size_t)(b * 8 + hd2)) * NB + n0 + mm) * 64 + g4 * 4);
        *(float4*)&swt[(hd2 * 16 + mm) * 64 + g4 * 4] = dec4(u);
    }
    __syncthreads();
    float acc[16];
#pragma unroll
    for (int mm = 0; mm < 16; ++mm) acc[mm] = 0.f;
    const float* osb = OS + ((size_t)(b * 8 + hd)) * 2048 + d;
#pragma unroll 4
    for (int g4 = 0; g4 < 16; ++g4) {
        float o0 = osb[(g4 * 4 + 0) * 32], o1 = osb[(g4 * 4 + 1) * 32];
        float o2 = osb[(g4 * 4 + 2) * 32], o3 = osb[(g4 * 4 + 3) * 32];
        const float* swp = swt + hd * 1024 + g4 * 4;
#pragma unroll
        for (int mm = 0; mm < 16; ++mm) {
            float4 sv = *(const float4*)(swp + mm * 64);
            acc[mm] = fmaf(o0, sv.x, fmaf(o1, sv.y, fmaf(o2, sv.z, fmaf(o3, sv.w, acc[mm]))));
        }
    }
#pragma unroll
    for (int mm = 0; mm < 16; ++mm)
        OX[((size_t)b * NB + n0 + mm) * 256 + t] = f2bf(acc[mm]);
}

// ---------------- head stage 2: out = hid @ head_w2 + b2 -------------------
__global__ __launch_bounds__(256) void head2_kernel(
    const u16* __restrict__ HID, const float* __restrict__ w2,
    const float* __restrict__ b2, const void* tmp, void* __restrict__ OUT)
{
    int isbf = (((const u16*)tmp)[0] != 0);
    int lane = threadIdx.x & 63;
    size_t m = (size_t)blockIdx.x * 4 + (threadIdx.x >> 6);
    const float4 hv = dec4(*(const ushort4*)(HID + m * 256 + lane * 4));
    float4 a = make_float4(0.f, 0.f, 0.f, 0.f);
    float hcomp[4] = {hv.x, hv.y, hv.z, hv.w};
#pragma unroll
    for (int i = 0; i < 4; ++i) {
        const float4 wv = *(const float4*)(w2 + (lane * 4 + i) * 4);
        float h = hcomp[i];
        a.x = fmaf(h, wv.x, a.x); a.y = fmaf(h, wv.y, a.y);
        a.z = fmaf(h, wv.z, a.z); a.w = fmaf(h, wv.w, a.w);
    }
#pragma unroll
    for (int o = 32; o; o >>= 1) {
        a.x += __shfl_xor(a.x, o); a.y += __shfl_xor(a.y, o);
        a.z += __shfl_xor(a.z, o); a.w += __shfl_xor(a.w, o);
    }
    if (lane == 0) {
        float o0 = a.x + b2[0], o1 = a.y + b2[1], o2 = a.z + b2[2], o3 = a.w + b2[3];
        if (isbf) {
            ushort4 r; r.x = f2bf(o0); r.y = f2bf(o1); r.z = f2bf(o2); r.w = f2bf(o3);
            *(ushort4*)((u16*)OUT + m * 4) = r;
        } else {
            *(float4*)((float*)OUT + m * 4) = make_float4(o0, o1, o2, o3);
        }
    }
}

// ---------------------------------------------------------------------------
extern "C" void kernel_launch(void* const* d_in, const int* in_sizes, int n_in,
                              void* d_out, int out_size, void* d_ws, size_t ws_size,
                              hipStream_t stream)
{
    const void* x = d_in[0];      const void* fx = d_in[1];
    const void* pre_w1 = d_in[2]; const void* pre_b1 = d_in[3];
    const void* pre_w2 = d_in[4]; const void* pre_b2 = d_in[5];
    const void* placeholder = d_in[6];
    const void* ln1_g = d_in[7];  const void* ln1_b = d_in[8];
    const void* px_w = d_in[9];   const void* px_b = d_in[10];
    const void* pfx_w = d_in[11]; const void* pfx_b = d_in[12];
    const void* slice_w = d_in[13]; const void* slice_b = d_in[14];
    const void* temp = d_in[15];
    const void* q_w = d_in[16];   const void* k_w = d_in[17]; const void* v_w = d_in[18];
    const void* out_w = d_in[19]; const void* out_b = d_in[20];
    const void* ln2_g = d_in[21]; const void* ln2_b = d_in[22];
    const void* mlp_w1 = d_in[23]; const void* mlp_b1 = d_in[24];
    const void* mlp_w2 = d_in[25]; const void* mlp_b2 = d_in[26];
    const void* ln3_g = d_in[27]; const void* ln3_b = d_in[28];
    const void* head_w1 = d_in[29]; const void* head_b1 = d_in[30];
    const void* head_w2 = d_in[31]; const void* head_b2 = d_in[32];

    float* ws = (float*)d_ws;
    float* H     = ws + F_H;
    float* TOKp  = ws + F_TOK;
    float* NORMp = ws + F_NORM;
    float* OSp   = ws + F_OS;
    float* BIAS  = ws + F_BIAS;
    float* P     = ws + F_PARAMS;
    u16*   U     = (u16*)(ws + F_BF);
    u16*   WT    = U + U_WT;
    u16*   Yb    = U + U_Y;
    u16*   XMb   = U + U_XM;
    u16*   FMb   = U + U_FM;
    u16*   SWb   = U + U_SW;
    u16*   HIDb  = U + U_XM;   // [M,512] spans XM+FM (free before layer loop)

    cvt_kernel<<<910, 256, 0, stream>>>(x, fx, pre_w1, pre_b1, ln1_g, ln1_b,
        ln2_g, ln2_b, ln3_g, ln3_b, slice_w, slice_b, temp, q_w, k_w, v_w,
        head_w2, head_b2, P);
    prep_kernel<<<8480, 256, 0, stream>>>(pre_w2, head_w1, px_w, pfx_w, out_w,
        mlp_w1, mlp_w2, pre_b2, placeholder, px_b, pfx_b, out_b, mlp_b1, mlp_b2,
        head_b1, slice_w, slice_b, temp, WT, BIAS);
    pre1_kernel<<<65536, 256, 0, stream>>>(P, HIDb);

    dim3 gg(256, 2);
    dim3 gs(256, 4);
    gemm_mfma<512, 0><<<gg, 256, 0, stream>>>(HIDb, WT + WT_PRE2, BIAS + B_PB2C, H, nullptr);

    for (int i = 0; i < 5; ++i) {
        ln_kernel<<<8192, 256, 0, stream>>>(H, P + P_LN1G + i * 256, P + P_LN1B + i * 256, Yb);
        gemm_slice<<<gs, 256, 0, stream>>>(Yb, WT + WT_PXSL + i * 131072, BIAS + B_SL + i * 512, P + P_TEMP + i * 8, SWb);
        gemm_mfma<256, 2><<<gg, 256, 0, stream>>>(Yb, WT + WT_PFX + i * 65536, BIAS + B_PFXB + i * 256, nullptr, FMb);
        hipMemsetAsync(TOKp, 0, (size_t)33792 * 4, stream);
        tok_kernel<<<1024, 256, 0, stream>>>(FMb, SWb, TOKp, NORMp);
        attn_kernel<<<16, 256, 0, stream>>>(TOKp, NORMp, P + P_QW + i * 1024, P + P_KW + i * 1024, P + P_VW + i * 1024, OSp);
        deslice_kernel<<<2048, 256, 0, stream>>>(OSp, SWb, Yb);
        gemm_mfma<256, 1><<<gg, 256, 0, stream>>>(Yb, WT + WT_OUT + i * 65536, BIAS + B_OUTB + i * 256, H, nullptr);
        ln_kernel<<<8192, 256, 0, stream>>>(H, P + P_LN2G + i * 256, P + P_LN2B + i * 256, Yb);
        gemm_mfma<256, 3><<<gg, 256, 0, stream>>>(Yb,  WT + WT_MLP1 + i * 65536, BIAS + B_M1B + i * 256, nullptr, XMb);
        gemm_mfma<256, 1><<<gg, 256, 0, stream>>>(XMb, WT + WT_MLP2 + i * 65536, BIAS + B_M2B + i * 256, H, nullptr);
    }

    ln_kernel<<<8192, 256, 0, stream>>>(H, P + P_LN3G, P + P_LN3B, Yb);
    gemm_mfma<256, 3><<<gg, 256, 0, stream>>>(Yb, WT + WT_HEAD1, BIAS + B_HB1, nullptr, XMb);
    head2_kernel<<<8192, 256, 0, stream>>>(XMb, P + P_HW2, P + P_HB2, temp, d_out);
}